// Round 3
// baseline (564.438 us; speedup 1.0000x reference)
//
#include <hip/hip_runtime.h>

typedef unsigned short ushort_t;
typedef unsigned int uint_t;

#define T_DATA 100000
#define E_NO 2000
#define I_NO 400
#define SUB 20
#define TNO 200
#define NBASIS 19
#define HEAD 256
#define TAILPAD 2048
#define SIGSTRIDE (HEAD + T_DATA + TAILPAD)   // 102304 bf16 per (signal, subunit)
#define TILE 2048
#define RPT 8
#define TSPAN 128
#define SLOTSTR 132                            // padded t-stride for k1 LDS acc

#define OFF_Z  ((size_t)T_DATA)                       // element offset of final_Z
#define OFF_F  ((size_t)T_DATA + (size_t)T_DATA*SUB)  // element offset of out_filters

__device__ __forceinline__ float b2f(ushort_t u) {
    union { uint_t i; float f; } v; v.i = ((uint_t)u) << 16; return v.f;
}
__device__ __forceinline__ ushort_t f2b(float f) {
    union { uint_t i; float f_; } v; v.f_ = f;
    uint_t b = v.i;
    uint_t r = (b + 0x7FFFu + ((b >> 16) & 1u)) >> 16;
    return (ushort_t)r;
}
// mode: 1 = bf16 buffers, 0 = f32 buffers
__device__ __forceinline__ float ldin(const void* p, size_t idx, int mode) {
    return mode ? b2f(((const ushort_t*)p)[idx]) : ((const float*)p)[idx];
}
__device__ __forceinline__ void stout(void* p, size_t idx, float val, int mode) {
    if (mode) ((ushort_t*)p)[idx] = f2b(val);
    else      ((float*)p)[idx] = val;
}
__device__ __forceinline__ float f4get(const float4& v, int i) {
    return i == 0 ? v.x : i == 1 ? v.y : i == 2 ? v.z : v.w;
}
__device__ __forceinline__ float pick12(const float4& L, const float4& M, const float4& H, int e) {
    return e < 4 ? f4get(L, e) : e < 8 ? f4get(M, e - 4) : f4get(H, e - 8);
}

// ---------------- probe: detect input dtype from Tau_spk (~3.0 each) ----------------
__global__ void k_probe(const void* tau, int* flag) {
    if (threadIdx.x == 0) {
        const ushort_t* tu = (const ushort_t*)tau;
        int cnt = 0;
        for (int i = 0; i < 20; ++i) {
            float v = b2f(tu[i]);
            if (v >= 1.5f && v < 6.0f) cnt++;
        }
        // bf16: all 20 in range. f32: only the 10 odd (high-half) ushorts.
        *flag = (cnt >= 15) ? 1 : 0;
    }
}

// ---------------- kernel 0: basis/filters, maps, pad zeroing ----------------
__global__ __launch_bounds__(256) void k0_prep(
        const int* __restrict__ flag,
        const void* Csyn_e, const void* Csyn_i,
        const void* W_syn, const void* W_hist,
        const void* W_spk, const void* Delta, const void* Tau,
        float* ws_f, int* mape, int* mapi, ushort_t* sigs, void* dout) {
    int mode = *flag;
    int bid = blockIdx.x, tid = threadIdx.x;
    if (bid < 80) {                       // filter rows: bid = kidx*20 + s
        int kidx = bid / 20, s = bid % 20;
        int tau = tid;
        if (tau < TNO) {
            float val;
            if (kidx < 3) {
                float raw = 5.0f * logf((float)tau + 1.0f);
                val = 0.f;
                for (int b = 0; b < NBASIS; ++b) {
                    float phi = 1.5707963267948966f * (float)b;
                    float d = raw - phi;
                    float basis = (d >= -3.14159265358979f && d <= 3.14159265358979f)
                                  ? (0.5f * cosf(d) + 0.5f) : 0.f;
                    float w = (kidx == 0) ? ldin(W_syn, (size_t)s * NBASIS * 2 + b * 2 + 0, mode)
                            : (kidx == 1) ? ldin(W_syn, (size_t)s * NBASIS * 2 + b * 2 + 1, mode)
                                          : ldin(W_hist, (size_t)s * NBASIS + b, mode);
                    val += w * basis;
                }
            } else {
                float dl = ldin(Delta, s, mode), tu = ldin(Tau, s, mode), wk = ldin(W_spk, s, mode);
                float t = fmaxf((float)tau - dl, 0.f);
                float tt = t / (tu * tu);
                val = tt * expf(-tt) * (wk * wk);
            }
            ws_f[kidx * 4000 + s * TNO + tau] = val;
            stout(dout, OFF_F + (size_t)bid * TNO + tau, val, mode);
        }
    } else if (bid < 96) {                // map_e
        int e = (bid - 80) * 256 + tid;
        if (e < E_NO) {
            int m = 0;
            for (int s = 0; s < SUB; ++s)
                if (ldin(Csyn_e, (size_t)s * E_NO + e, mode) != 0.f) { m = s; break; }
            mape[e] = m;
        }
    } else if (bid < 98) {                // map_i
        int e = (bid - 96) * 256 + tid;
        if (e < I_NO) {
            int m = 0;
            for (int s = 0; s < SUB; ++s)
                if (ldin(Csyn_i, (size_t)s * I_NO + e, mode) != 0.f) { m = s; break; }
            mapi[e] = m;
        }
    } else if (bid < 158) {               // zero head+tail pads: 60 regions
        int rg = bid - 98;                // 0..59 = sig*20 + s
        int sg = rg / 20, s = rg % 20;
        ushort_t* p = sigs + (size_t)sg * SUB * SIGSTRIDE + (size_t)s * SIGSTRIDE;
        for (int i = tid; i < HEAD; i += 256) p[i] = 0;
        for (int i = tid; i < TAILPAD; i += 256) p[HEAD + T_DATA + i] = 0;
    }
}

// ---------------- kernel 1 v2: span-per-block bucket reduce, coalesced writes ----------------
// Block owns rows [base, base+TSPAN). One wave per row (rows rl%4==wave), LDS
// atomics into acc[slot][rl] (slot: 0..19 E, 20..39 I, 40..59 Z). Two barriers
// total. Phase B: packed-bf16 coalesced writes, 256B runs per signal row.
__global__ __launch_bounds__(256) void k1_reduce(
        const int* __restrict__ flag,
        const void* __restrict__ S_e, const void* __restrict__ S_i,
        const void* __restrict__ Z,
        const int* __restrict__ mape, const int* __restrict__ mapi,
        ushort_t* __restrict__ sigs) {
    __shared__ int me[E_NO];
    __shared__ int mi[I_NO];
    __shared__ float acc[60 * SLOTSTR];
    int tid = threadIdx.x;
    int mode = *flag;
    int wave = tid >> 6, lane = tid & 63;
    for (int i = tid; i < E_NO; i += 256) me[i] = mape[i];
    for (int i = tid; i < I_NO; i += 256) mi[i] = mapi[i];
    for (int i = tid; i < 60 * SLOTSTR; i += 256) acc[i] = 0.f;
    __syncthreads();

    int base = blockIdx.x * TSPAN;
    for (int it = 0; it < TSPAN / 4; ++it) {
        int rl = it * 4 + wave;
        int row = base + rl;
        if (row >= T_DATA) continue;
        if (mode) {
            const ushort_t* pe = (const ushort_t*)S_e + (size_t)row * E_NO;
            #pragma unroll
            for (int rd = 0; rd < 4; ++rd) {
                int idx = rd * 64 + lane;
                if (idx < 250) {
                    uint4 u = *(const uint4*)(pe + idx * 8);
                    uint_t wd[4] = {u.x, u.y, u.z, u.w};
                    #pragma unroll
                    for (int q = 0; q < 4; ++q) {
                        float a = b2f((ushort_t)(wd[q] & 0xFFFF));
                        float b = b2f((ushort_t)(wd[q] >> 16));
                        if (a != 0.f) atomicAdd(&acc[me[idx * 8 + 2 * q] * SLOTSTR + rl], a);
                        if (b != 0.f) atomicAdd(&acc[me[idx * 8 + 2 * q + 1] * SLOTSTR + rl], b);
                    }
                }
            }
            const ushort_t* pi = (const ushort_t*)S_i + (size_t)row * I_NO;
            if (lane < 50) {
                uint4 u = *(const uint4*)(pi + lane * 8);
                uint_t wd[4] = {u.x, u.y, u.z, u.w};
                #pragma unroll
                for (int q = 0; q < 4; ++q) {
                    float a = b2f((ushort_t)(wd[q] & 0xFFFF));
                    float b = b2f((ushort_t)(wd[q] >> 16));
                    if (a != 0.f) atomicAdd(&acc[(20 + mi[lane * 8 + 2 * q]) * SLOTSTR + rl], a);
                    if (b != 0.f) atomicAdd(&acc[(20 + mi[lane * 8 + 2 * q + 1]) * SLOTSTR + rl], b);
                }
            }
        } else {
            const float* pe = (const float*)S_e + (size_t)row * E_NO;
            #pragma unroll
            for (int rd = 0; rd < 8; ++rd) {
                int idx = rd * 64 + lane;          // float4 index, 500 total
                if (idx < 500) {
                    float4 u = *(const float4*)(pe + idx * 4);
                    float v[4] = {u.x, u.y, u.z, u.w};
                    #pragma unroll
                    for (int q = 0; q < 4; ++q)
                        if (v[q] != 0.f) atomicAdd(&acc[me[idx * 4 + q] * SLOTSTR + rl], v[q]);
                }
            }
            const float* pi = (const float*)S_i + (size_t)row * I_NO;
            #pragma unroll
            for (int rd = 0; rd < 2; ++rd) {
                int idx = rd * 64 + lane;          // float4 index, 100 total
                if (idx < 100) {
                    float4 u = *(const float4*)(pi + idx * 4);
                    float v[4] = {u.x, u.y, u.z, u.w};
                    #pragma unroll
                    for (int q = 0; q < 4; ++q)
                        if (v[q] != 0.f) atomicAdd(&acc[(20 + mi[idx * 4 + q]) * SLOTSTR + rl], v[q]);
                }
            }
        }
        if (lane < 20)
            acc[(40 + lane) * SLOTSTR + rl] = ldin(Z, (size_t)row * SUB + lane, mode);
    }
    __syncthreads();

    // Phase B: 60 signal rows x TSPAN t, packed bf16, 4 t per uint2 store
    for (int idx = tid; idx < 60 * (TSPAN / 4); idx += 256) {
        int sig = idx >> 5;                // / (TSPAN/4) == /32
        int g = idx & 31;
        int t0 = g * 4;
        if (base + t0 >= T_DATA) continue; // T_DATA%4==0 -> never partial
        const float* src = &acc[sig * SLOTSTR + t0];
        float4 v = *(const float4*)src;
        uint2 o;
        o.x = (uint_t)f2b(v.x) | ((uint_t)f2b(v.y) << 16);
        o.y = (uint_t)f2b(v.z) | ((uint_t)f2b(v.w) << 16);
        *(uint2*)(sigs + (size_t)sig * SIGSTRIDE + HEAD + base + t0) = o;
    }
}

// ---------------- kernel 2: 4x 200-tap depthwise FIR, f32 accum ----------------
__global__ __launch_bounds__(256) void k2_conv(
        const ushort_t* __restrict__ sigs, const float* __restrict__ ws_f,
        ushort_t* __restrict__ base_out, ushort_t* __restrict__ spk_out) {
    __shared__ float X[3 * 2248 + 800];
    float* XE = X;
    float* XI = X + 2248;
    float* ZZ = X + 4496;
    float* KK = X + 6744;
    int s = blockIdx.y;
    int t0 = blockIdx.x * TILE;
    int tid = threadIdx.x;

    for (int k = 0; k < 4; ++k)
        for (int j = tid; j < TNO; j += 256)
            KK[k * TNO + j] = ws_f[k * 4000 + s * TNO + j];

    {
        const ushort_t* g0 = sigs + (size_t)s * SIGSTRIDE + (HEAD - 200) + t0;
        const ushort_t* g1 = g0 + (size_t)SUB * SIGSTRIDE;
        const ushort_t* g2 = g0 + (size_t)2 * SUB * SIGSTRIDE;
        for (int v = tid; v < 281; v += 256) {
            uint4 u = *(const uint4*)(g0 + v * 8);
            float* d = XE + v * 8;
            d[0]=b2f((ushort_t)(u.x&0xFFFF)); d[1]=b2f((ushort_t)(u.x>>16));
            d[2]=b2f((ushort_t)(u.y&0xFFFF)); d[3]=b2f((ushort_t)(u.y>>16));
            d[4]=b2f((ushort_t)(u.z&0xFFFF)); d[5]=b2f((ushort_t)(u.z>>16));
            d[6]=b2f((ushort_t)(u.w&0xFFFF)); d[7]=b2f((ushort_t)(u.w>>16));
        }
        for (int v = tid; v < 281; v += 256) {
            uint4 u = *(const uint4*)(g1 + v * 8);
            float* d = XI + v * 8;
            d[0]=b2f((ushort_t)(u.x&0xFFFF)); d[1]=b2f((ushort_t)(u.x>>16));
            d[2]=b2f((ushort_t)(u.y&0xFFFF)); d[3]=b2f((ushort_t)(u.y>>16));
            d[4]=b2f((ushort_t)(u.z&0xFFFF)); d[5]=b2f((ushort_t)(u.z>>16));
            d[6]=b2f((ushort_t)(u.w&0xFFFF)); d[7]=b2f((ushort_t)(u.w>>16));
        }
        for (int v = tid; v < 281; v += 256) {
            uint4 u = *(const uint4*)(g2 + v * 8);
            float* d = ZZ + v * 8;
            d[0]=b2f((ushort_t)(u.x&0xFFFF)); d[1]=b2f((ushort_t)(u.x>>16));
            d[2]=b2f((ushort_t)(u.y&0xFFFF)); d[3]=b2f((ushort_t)(u.y>>16));
            d[4]=b2f((ushort_t)(u.z&0xFFFF)); d[5]=b2f((ushort_t)(u.z>>16));
            d[6]=b2f((ushort_t)(u.w&0xFFFF)); d[7]=b2f((ushort_t)(u.w>>16));
        }
    }
    __syncthreads();

    float acc[RPT] = {0,0,0,0,0,0,0,0};
    float spk[RPT] = {0,0,0,0,0,0,0,0};
    const float4* XE4 = (const float4*)XE;
    const float4* XI4 = (const float4*)XI;
    const float4* ZZ4 = (const float4*)ZZ;
    const float4* KE4 = (const float4*)(KK);
    const float4* KI4 = (const float4*)(KK + 200);
    const float4* KH4 = (const float4*)(KK + 400);
    const float4* KS4 = (const float4*)(KK + 600);
    int w4 = 2 * tid + 49;                 // float4 index of window base W = 8*tid+196
    float4 eL = XE4[w4], eM = XE4[w4 + 1], eH = XE4[w4 + 2];
    float4 iL = XI4[w4], iM = XI4[w4 + 1], iH = XI4[w4 + 2];
    float4 zL = ZZ4[w4], zM = ZZ4[w4 + 1], zH = ZZ4[w4 + 2];

    for (int c = 0; c < 50; ++c) {
        if (c > 0) {
            eH = eM; eM = eL; eL = XE4[w4 - c];
            iH = iM; iM = iL; iL = XI4[w4 - c];
            zH = zM; zM = zL; zL = ZZ4[w4 - c];
        }
        float4 ke = KE4[c], ki = KI4[c], kh = KH4[c], ks = KS4[c];
        #pragma unroll
        for (int u = 0; u < 4; ++u) {
            float keu = f4get(ke, u), kiu = f4get(ki, u);
            float khu = f4get(kh, u), ksu = f4get(ks, u);
            #pragma unroll
            for (int r = 0; r < RPT; ++r) {
                float xe = pick12(eL, eM, eH, 4 + r - u);
                float xi = pick12(iL, iM, iH, 4 + r - u);
                float zz = pick12(zL, zM, zH, 3 + r - u);
                acc[r] += keu * xe;
                acc[r] += kiu * xi;
                acc[r] += khu * zz;
                spk[r] += ksu * zz;
            }
        }
    }
    int tbase = t0 + RPT * tid;
    if (tbase + RPT <= T_DATA) {
        uint4 pb, pq;
        pb.x = (uint_t)f2b(acc[0]) | ((uint_t)f2b(acc[1]) << 16);
        pb.y = (uint_t)f2b(acc[2]) | ((uint_t)f2b(acc[3]) << 16);
        pb.z = (uint_t)f2b(acc[4]) | ((uint_t)f2b(acc[5]) << 16);
        pb.w = (uint_t)f2b(acc[6]) | ((uint_t)f2b(acc[7]) << 16);
        pq.x = (uint_t)f2b(spk[0]) | ((uint_t)f2b(spk[1]) << 16);
        pq.y = (uint_t)f2b(spk[2]) | ((uint_t)f2b(spk[3]) << 16);
        pq.z = (uint_t)f2b(spk[4]) | ((uint_t)f2b(spk[5]) << 16);
        pq.w = (uint_t)f2b(spk[6]) | ((uint_t)f2b(spk[7]) << 16);
        *(uint4*)(base_out + (size_t)s * T_DATA + tbase) = pb;
        *(uint4*)(spk_out + (size_t)s * T_DATA + tbase) = pq;
    } else {
        #pragma unroll
        for (int r = 0; r < RPT; ++r) {
            int t = tbase + r;
            if (t < T_DATA) {
                base_out[(size_t)s * T_DATA + t] = f2b(acc[r]);
                spk_out[(size_t)s * T_DATA + t] = f2b(spk[r]);
            }
        }
    }
}

// ---------------- kernel 3: tree gather + MLP + outputs ----------------
__global__ __launch_bounds__(256) void k3_mlp(
        const int* __restrict__ flag,
        const ushort_t* __restrict__ base_out, const ushort_t* __restrict__ spk_out,
        const void* __restrict__ C_den, const void* __restrict__ Theta,
        const void* __restrict__ Vo,
        const void* __restrict__ w1, const void* __restrict__ w2,
        const void* __restrict__ w3,
        void* __restrict__ dout) {
    __shared__ float cd[400], th[20], W1[120], W2[36], W3[120];
    __shared__ float vo;
    int tid = threadIdx.x;
    int mode = *flag;
    for (int i = tid; i < 400; i += 256) cd[i] = ldin(C_den, i, mode);
    if (tid < 20) th[tid] = ldin(Theta, tid, mode);
    if (tid < 120) W1[tid] = ldin(w1, tid, mode);
    if (tid < 36) W2[tid] = ldin(w2, tid, mode);
    if (tid >= 128 && tid < 248) W3[tid - 128] = ldin(w3, tid - 128, mode);
    if (tid == 0) vo = ldin(Vo, 0, mode);
    __syncthreads();
    int t = blockIdx.x * 256 + tid;
    if (t >= T_DATA) return;
    float sv[20], bv[20];
    #pragma unroll
    for (int c = 0; c < 20; ++c) {
        sv[c] = b2f(spk_out[(size_t)c * T_DATA + t]);
        bv[c] = b2f(base_out[(size_t)c * T_DATA + t]);
    }
    stout(dout, (size_t)t, sv[0] + vo, mode);
    #pragma unroll
    for (int p = 0; p < 20; ++p) {
        float ps = 0.f;
        #pragma unroll
        for (int c = 0; c < 20; ++c) ps += cd[p * 20 + c] * sv[c];
        float x = bv[p] + th[p] + ps;
        float h0 = x >= 0.f ? x : 0.01f * x;
        float h1[6];
        #pragma unroll
        for (int k = 0; k < 6; ++k) {
            float y = h0 * W1[p * 6 + k];
            h1[k] = y >= 0.f ? y : 0.01f * y;
        }
        float zacc = 0.f;
        #pragma unroll
        for (int j = 0; j < 6; ++j) {
            float a = 0.f;
            #pragma unroll
            for (int k = 0; k < 6; ++k) a += h1[k] * W2[k * 6 + j];
            float h2 = a >= 0.f ? a : 0.01f * a;
            zacc += h2 * W3[j * 20 + p];
        }
        float zv = 1.f / (1.f + expf(-zacc));
        stout(dout, OFF_Z + (size_t)t * SUB + p, zv, mode);
    }
}

extern "C" void kernel_launch(void* const* d_in, const int* in_sizes, int n_in,
                              void* d_out, int out_size, void* d_ws, size_t ws_size,
                              hipStream_t stream) {
    const void* S_e     = d_in[0];
    const void* S_i     = d_in[1];
    const void* Z       = d_in[2];
    const void* C_den   = d_in[3];
    const void* C_syn_e = d_in[4];
    const void* C_syn_i = d_in[5];
    const void* W_syn   = d_in[6];
    const void* W_hist  = d_in[7];
    const void* W_spk   = d_in[8];
    const void* Delta   = d_in[9];
    const void* Tau     = d_in[10];
    const void* Vo      = d_in[11];
    const void* Theta   = d_in[12];
    const void* w1      = d_in[13];
    const void* w2      = d_in[14];
    const void* w3      = d_in[15];

    char* w = (char*)d_ws;
    int*      flag     = (int*)w;                       // 64 B slot
    float*    ws_f     = (float*)(w + 64);              // 16000 f32 filters
    int*      mape     = (int*)(w + 64 + 64000);        // 2000 int
    int*      mapi     = (int*)(w + 64 + 64000 + 8000); // 400 int
    ushort_t* sigs     = (ushort_t*)(w + 73664);        // 60 * SIGSTRIDE bf16
    ushort_t* base_out = (ushort_t*)(w + 12350144);     // [20][T] bf16
    ushort_t* spk_out  = (ushort_t*)(w + 16350144);     // [20][T] bf16 (end 20350144 B)

    hipLaunchKernelGGL(k_probe, dim3(1), dim3(64), 0, stream, Tau, flag);
    hipLaunchKernelGGL(k0_prep, dim3(158), dim3(256), 0, stream,
                       flag, C_syn_e, C_syn_i, W_syn, W_hist, W_spk, Delta, Tau,
                       ws_f, mape, mapi, sigs, d_out);
    hipLaunchKernelGGL(k1_reduce, dim3((T_DATA + TSPAN - 1) / TSPAN), dim3(256), 0, stream,
                       flag, S_e, S_i, Z, mape, mapi, sigs);
    hipLaunchKernelGGL(k2_conv, dim3((T_DATA + TILE - 1) / TILE, SUB), dim3(256), 0, stream,
                       sigs, ws_f, base_out, spk_out);
    hipLaunchKernelGGL(k3_mlp, dim3((T_DATA + 255) / 256), dim3(256), 0, stream,
                       flag, base_out, spk_out, C_den, Theta, Vo, w1, w2, w3, d_out);
}

// Round 4
// 299.769 us; speedup vs baseline: 1.8829x; 1.8829x over previous
//
#include <hip/hip_runtime.h>

typedef unsigned short ushort_t;
typedef unsigned int uint_t;

#define T_DATA 100000
#define E_NO 2000
#define I_NO 400
#define SUB 20
#define TNO 200
#define NBASIS 19
#define HEAD 256
#define TAILPAD 2048
#define SIGSTRIDE (HEAD + T_DATA + TAILPAD)   // 102304 bf16 per (signal, subunit)
#define TILE 2048
#define RPT 8
#define TSPAN 32                               // rows per k1 block (100000 = 3125*32)
#define ACCSTR 36                              // padded t-stride for k1 LDS acc

#define OFF_Z  ((size_t)T_DATA)                       // element offset of final_Z
#define OFF_F  ((size_t)T_DATA + (size_t)T_DATA*SUB)  // element offset of out_filters

__device__ __forceinline__ float b2f(ushort_t u) {
    union { uint_t i; float f; } v; v.i = ((uint_t)u) << 16; return v.f;
}
__device__ __forceinline__ ushort_t f2b(float f) {
    union { uint_t i; float f_; } v; v.f_ = f;
    uint_t b = v.i;
    uint_t r = (b + 0x7FFFu + ((b >> 16) & 1u)) >> 16;
    return (ushort_t)r;
}
// mode: 1 = bf16 buffers, 0 = f32 buffers
__device__ __forceinline__ float ldin(const void* p, size_t idx, int mode) {
    return mode ? b2f(((const ushort_t*)p)[idx]) : ((const float*)p)[idx];
}
__device__ __forceinline__ void stout(void* p, size_t idx, float val, int mode) {
    if (mode) ((ushort_t*)p)[idx] = f2b(val);
    else      ((float*)p)[idx] = val;
}
__device__ __forceinline__ float f4get(const float4& v, int i) {
    return i == 0 ? v.x : i == 1 ? v.y : i == 2 ? v.z : v.w;
}
__device__ __forceinline__ float pick12(const float4& L, const float4& M, const float4& H, int e) {
    return e < 4 ? f4get(L, e) : e < 8 ? f4get(M, e - 4) : f4get(H, e - 8);
}

// ---------------- probe: detect input dtype from Tau_spk (~3.0 each) ----------------
__global__ void k_probe(const void* tau, int* flag) {
    if (threadIdx.x == 0) {
        const ushort_t* tu = (const ushort_t*)tau;
        int cnt = 0;
        for (int i = 0; i < 20; ++i) {
            float v = b2f(tu[i]);
            if (v >= 1.5f && v < 6.0f) cnt++;
        }
        // bf16: all 20 in range. f32: only the 10 odd (high-half) ushorts.
        *flag = (cnt >= 15) ? 1 : 0;
    }
}

// ---------------- kernel 0: basis/filters, maps, pad zeroing ----------------
__global__ __launch_bounds__(256) void k0_prep(
        const int* __restrict__ flag,
        const void* Csyn_e, const void* Csyn_i,
        const void* W_syn, const void* W_hist,
        const void* W_spk, const void* Delta, const void* Tau,
        float* ws_f, int* mape, int* mapi, ushort_t* sigs, void* dout) {
    int mode = *flag;
    int bid = blockIdx.x, tid = threadIdx.x;
    if (bid < 80) {                       // filter rows: bid = kidx*20 + s
        int kidx = bid / 20, s = bid % 20;
        int tau = tid;
        if (tau < TNO) {
            float val;
            if (kidx < 3) {
                float raw = 5.0f * logf((float)tau + 1.0f);
                val = 0.f;
                for (int b = 0; b < NBASIS; ++b) {
                    float phi = 1.5707963267948966f * (float)b;
                    float d = raw - phi;
                    float basis = (d >= -3.14159265358979f && d <= 3.14159265358979f)
                                  ? (0.5f * cosf(d) + 0.5f) : 0.f;
                    float w = (kidx == 0) ? ldin(W_syn, (size_t)s * NBASIS * 2 + b * 2 + 0, mode)
                            : (kidx == 1) ? ldin(W_syn, (size_t)s * NBASIS * 2 + b * 2 + 1, mode)
                                          : ldin(W_hist, (size_t)s * NBASIS + b, mode);
                    val += w * basis;
                }
            } else {
                float dl = ldin(Delta, s, mode), tu = ldin(Tau, s, mode), wk = ldin(W_spk, s, mode);
                float t = fmaxf((float)tau - dl, 0.f);
                float tt = t / (tu * tu);
                val = tt * expf(-tt) * (wk * wk);
            }
            ws_f[kidx * 4000 + s * TNO + tau] = val;
            stout(dout, OFF_F + (size_t)bid * TNO + tau, val, mode);
        }
    } else if (bid < 96) {                // map_e
        int e = (bid - 80) * 256 + tid;
        if (e < E_NO) {
            int m = 0;
            for (int s = 0; s < SUB; ++s)
                if (ldin(Csyn_e, (size_t)s * E_NO + e, mode) != 0.f) { m = s; break; }
            mape[e] = m;
        }
    } else if (bid < 98) {                // map_i
        int e = (bid - 96) * 256 + tid;
        if (e < I_NO) {
            int m = 0;
            for (int s = 0; s < SUB; ++s)
                if (ldin(Csyn_i, (size_t)s * I_NO + e, mode) != 0.f) { m = s; break; }
            mapi[e] = m;
        }
    } else if (bid < 158) {               // zero head+tail pads: 60 regions
        int rg = bid - 98;                // 0..59 = sig*20 + s
        int sg = rg / 20, s = rg % 20;
        ushort_t* p = sigs + (size_t)sg * SUB * SIGSTRIDE + (size_t)s * SIGSTRIDE;
        for (int i = tid; i < HEAD; i += 256) p[i] = 0;
        for (int i = tid; i < TAILPAD; i += 256) p[HEAD + T_DATA + i] = 0;
    }
}

// ---------------- kernel 1 v3: 32-row span, all threads per row, no per-row barriers ----
// Block owns rows [base, base+32). All 256 threads cooperate on each row's loads
// (250 uint4 for S_e bf16). acc[slot][rl] in LDS (slot 0..19 E, 20..39 I, 40..59 Z),
// LDS atomics; waves drift freely across rows (no intra-loop barrier). One barrier,
// then coalesced packed-bf16 writes: 64B aligned run per signal row per block.
__global__ __launch_bounds__(256) void k1_reduce(
        const int* __restrict__ flag,
        const void* __restrict__ S_e, const void* __restrict__ S_i,
        const void* __restrict__ Z,
        const int* __restrict__ mape, const int* __restrict__ mapi,
        ushort_t* __restrict__ sigs) {
    __shared__ int me[E_NO];
    __shared__ int mi[I_NO];
    __shared__ float acc[60 * ACCSTR];
    int tid = threadIdx.x;
    int mode = *flag;
    for (int i = tid; i < E_NO; i += 256) me[i] = mape[i];
    for (int i = tid; i < I_NO; i += 256) mi[i] = mapi[i];
    for (int i = tid; i < 60 * ACCSTR; i += 256) acc[i] = 0.f;
    __syncthreads();

    int base = blockIdx.x * TSPAN;
    for (int rl = 0; rl < TSPAN; ++rl) {
        int row = base + rl;
        if (mode) {
            if (tid < 250) {
                uint4 u = *(const uint4*)((const ushort_t*)S_e + (size_t)row * E_NO + tid * 8);
                uint_t wd[4] = {u.x, u.y, u.z, u.w};
                #pragma unroll
                for (int q = 0; q < 4; ++q) {
                    float a = b2f((ushort_t)(wd[q] & 0xFFFF));
                    float b = b2f((ushort_t)(wd[q] >> 16));
                    if (a != 0.f) atomicAdd(&acc[me[tid * 8 + 2 * q] * ACCSTR + rl], a);
                    if (b != 0.f) atomicAdd(&acc[me[tid * 8 + 2 * q + 1] * ACCSTR + rl], b);
                }
            }
            if (tid < 50) {
                uint4 u = *(const uint4*)((const ushort_t*)S_i + (size_t)row * I_NO + tid * 8);
                uint_t wd[4] = {u.x, u.y, u.z, u.w};
                #pragma unroll
                for (int q = 0; q < 4; ++q) {
                    float a = b2f((ushort_t)(wd[q] & 0xFFFF));
                    float b = b2f((ushort_t)(wd[q] >> 16));
                    if (a != 0.f) atomicAdd(&acc[(20 + mi[tid * 8 + 2 * q]) * ACCSTR + rl], a);
                    if (b != 0.f) atomicAdd(&acc[(20 + mi[tid * 8 + 2 * q + 1]) * ACCSTR + rl], b);
                }
            }
        } else {
            if (tid < 250) {
                const float* pe = (const float*)S_e + (size_t)row * E_NO;
                float4 u0 = *(const float4*)(pe + tid * 4);
                float4 u1 = *(const float4*)(pe + (tid + 250) * 4);
                float v0[4] = {u0.x, u0.y, u0.z, u0.w};
                float v1[4] = {u1.x, u1.y, u1.z, u1.w};
                #pragma unroll
                for (int q = 0; q < 4; ++q) {
                    if (v0[q] != 0.f) atomicAdd(&acc[me[tid * 4 + q] * ACCSTR + rl], v0[q]);
                    if (v1[q] != 0.f) atomicAdd(&acc[me[(tid + 250) * 4 + q] * ACCSTR + rl], v1[q]);
                }
            }
            if (tid < 100) {
                float4 u = *(const float4*)((const float*)S_i + (size_t)row * I_NO + tid * 4);
                float v[4] = {u.x, u.y, u.z, u.w};
                #pragma unroll
                for (int q = 0; q < 4; ++q)
                    if (v[q] != 0.f) atomicAdd(&acc[(20 + mi[tid * 4 + q]) * ACCSTR + rl], v[q]);
            }
        }
        if (tid >= 192 && tid < 212) {    // Z passthrough (wave 3, avoids hot lanes)
            int s = tid - 192;
            acc[(40 + s) * ACCSTR + rl] = ldin(Z, (size_t)row * SUB + s, mode);
        }
    }
    __syncthreads();

    // Phase B: 60 signal rows x 32 t, packed bf16, 4 t per uint2 store.
    // 8 consecutive threads cover one sig row's 64B aligned run.
    for (int idx = tid; idx < 60 * (TSPAN / 4); idx += 256) {
        int sig = idx >> 3;                // / 8
        int g = idx & 7;
        int t0 = g * 4;
        const float* src = &acc[sig * ACCSTR + t0];
        float4 v = *(const float4*)src;
        uint2 o;
        o.x = (uint_t)f2b(v.x) | ((uint_t)f2b(v.y) << 16);
        o.y = (uint_t)f2b(v.z) | ((uint_t)f2b(v.w) << 16);
        *(uint2*)(sigs + (size_t)sig * SIGSTRIDE + HEAD + base + t0) = o;
    }
}

// ---------------- kernel 2: 4x 200-tap depthwise FIR, f32 accum ----------------
__global__ __launch_bounds__(256) void k2_conv(
        const ushort_t* __restrict__ sigs, const float* __restrict__ ws_f,
        ushort_t* __restrict__ base_out, ushort_t* __restrict__ spk_out) {
    __shared__ float X[3 * 2248 + 800];
    float* XE = X;
    float* XI = X + 2248;
    float* ZZ = X + 4496;
    float* KK = X + 6744;
    int s = blockIdx.y;
    int t0 = blockIdx.x * TILE;
    int tid = threadIdx.x;

    for (int k = 0; k < 4; ++k)
        for (int j = tid; j < TNO; j += 256)
            KK[k * TNO + j] = ws_f[k * 4000 + s * TNO + j];

    {
        const ushort_t* g0 = sigs + (size_t)s * SIGSTRIDE + (HEAD - 200) + t0;
        const ushort_t* g1 = g0 + (size_t)SUB * SIGSTRIDE;
        const ushort_t* g2 = g0 + (size_t)2 * SUB * SIGSTRIDE;
        for (int v = tid; v < 281; v += 256) {
            uint4 u = *(const uint4*)(g0 + v * 8);
            float* d = XE + v * 8;
            d[0]=b2f((ushort_t)(u.x&0xFFFF)); d[1]=b2f((ushort_t)(u.x>>16));
            d[2]=b2f((ushort_t)(u.y&0xFFFF)); d[3]=b2f((ushort_t)(u.y>>16));
            d[4]=b2f((ushort_t)(u.z&0xFFFF)); d[5]=b2f((ushort_t)(u.z>>16));
            d[6]=b2f((ushort_t)(u.w&0xFFFF)); d[7]=b2f((ushort_t)(u.w>>16));
        }
        for (int v = tid; v < 281; v += 256) {
            uint4 u = *(const uint4*)(g1 + v * 8);
            float* d = XI + v * 8;
            d[0]=b2f((ushort_t)(u.x&0xFFFF)); d[1]=b2f((ushort_t)(u.x>>16));
            d[2]=b2f((ushort_t)(u.y&0xFFFF)); d[3]=b2f((ushort_t)(u.y>>16));
            d[4]=b2f((ushort_t)(u.z&0xFFFF)); d[5]=b2f((ushort_t)(u.z>>16));
            d[6]=b2f((ushort_t)(u.w&0xFFFF)); d[7]=b2f((ushort_t)(u.w>>16));
        }
        for (int v = tid; v < 281; v += 256) {
            uint4 u = *(const uint4*)(g2 + v * 8);
            float* d = ZZ + v * 8;
            d[0]=b2f((ushort_t)(u.x&0xFFFF)); d[1]=b2f((ushort_t)(u.x>>16));
            d[2]=b2f((ushort_t)(u.y&0xFFFF)); d[3]=b2f((ushort_t)(u.y>>16));
            d[4]=b2f((ushort_t)(u.z&0xFFFF)); d[5]=b2f((ushort_t)(u.z>>16));
            d[6]=b2f((ushort_t)(u.w&0xFFFF)); d[7]=b2f((ushort_t)(u.w>>16));
        }
    }
    __syncthreads();

    float acc[RPT] = {0,0,0,0,0,0,0,0};
    float spk[RPT] = {0,0,0,0,0,0,0,0};
    const float4* XE4 = (const float4*)XE;
    const float4* XI4 = (const float4*)XI;
    const float4* ZZ4 = (const float4*)ZZ;
    const float4* KE4 = (const float4*)(KK);
    const float4* KI4 = (const float4*)(KK + 200);
    const float4* KH4 = (const float4*)(KK + 400);
    const float4* KS4 = (const float4*)(KK + 600);
    int w4 = 2 * tid + 49;                 // float4 index of window base W = 8*tid+196
    float4 eL = XE4[w4], eM = XE4[w4 + 1], eH = XE4[w4 + 2];
    float4 iL = XI4[w4], iM = XI4[w4 + 1], iH = XI4[w4 + 2];
    float4 zL = ZZ4[w4], zM = ZZ4[w4 + 1], zH = ZZ4[w4 + 2];

    for (int c = 0; c < 50; ++c) {
        if (c > 0) {
            eH = eM; eM = eL; eL = XE4[w4 - c];
            iH = iM; iM = iL; iL = XI4[w4 - c];
            zH = zM; zM = zL; zL = ZZ4[w4 - c];
        }
        float4 ke = KE4[c], ki = KI4[c], kh = KH4[c], ks = KS4[c];
        #pragma unroll
        for (int u = 0; u < 4; ++u) {
            float keu = f4get(ke, u), kiu = f4get(ki, u);
            float khu = f4get(kh, u), ksu = f4get(ks, u);
            #pragma unroll
            for (int r = 0; r < RPT; ++r) {
                float xe = pick12(eL, eM, eH, 4 + r - u);
                float xi = pick12(iL, iM, iH, 4 + r - u);
                float zz = pick12(zL, zM, zH, 3 + r - u);
                acc[r] += keu * xe;
                acc[r] += kiu * xi;
                acc[r] += khu * zz;
                spk[r] += ksu * zz;
            }
        }
    }
    int tbase = t0 + RPT * tid;
    if (tbase + RPT <= T_DATA) {
        uint4 pb, pq;
        pb.x = (uint_t)f2b(acc[0]) | ((uint_t)f2b(acc[1]) << 16);
        pb.y = (uint_t)f2b(acc[2]) | ((uint_t)f2b(acc[3]) << 16);
        pb.z = (uint_t)f2b(acc[4]) | ((uint_t)f2b(acc[5]) << 16);
        pb.w = (uint_t)f2b(acc[6]) | ((uint_t)f2b(acc[7]) << 16);
        pq.x = (uint_t)f2b(spk[0]) | ((uint_t)f2b(spk[1]) << 16);
        pq.y = (uint_t)f2b(spk[2]) | ((uint_t)f2b(spk[3]) << 16);
        pq.z = (uint_t)f2b(spk[4]) | ((uint_t)f2b(spk[5]) << 16);
        pq.w = (uint_t)f2b(spk[6]) | ((uint_t)f2b(spk[7]) << 16);
        *(uint4*)(base_out + (size_t)s * T_DATA + tbase) = pb;
        *(uint4*)(spk_out + (size_t)s * T_DATA + tbase) = pq;
    } else {
        #pragma unroll
        for (int r = 0; r < RPT; ++r) {
            int t = tbase + r;
            if (t < T_DATA) {
                base_out[(size_t)s * T_DATA + t] = f2b(acc[r]);
                spk_out[(size_t)s * T_DATA + t] = f2b(spk[r]);
            }
        }
    }
}

// ---------------- kernel 3: tree gather + MLP + outputs ----------------
__global__ __launch_bounds__(256) void k3_mlp(
        const int* __restrict__ flag,
        const ushort_t* __restrict__ base_out, const ushort_t* __restrict__ spk_out,
        const void* __restrict__ C_den, const void* __restrict__ Theta,
        const void* __restrict__ Vo,
        const void* __restrict__ w1, const void* __restrict__ w2,
        const void* __restrict__ w3,
        void* __restrict__ dout) {
    __shared__ float cd[400], th[20], W1[120], W2[36], W3[120];
    __shared__ float vo;
    int tid = threadIdx.x;
    int mode = *flag;
    for (int i = tid; i < 400; i += 256) cd[i] = ldin(C_den, i, mode);
    if (tid < 20) th[tid] = ldin(Theta, tid, mode);
    if (tid < 120) W1[tid] = ldin(w1, tid, mode);
    if (tid < 36) W2[tid] = ldin(w2, tid, mode);
    if (tid >= 128 && tid < 248) W3[tid - 128] = ldin(w3, tid - 128, mode);
    if (tid == 0) vo = ldin(Vo, 0, mode);
    __syncthreads();
    int t = blockIdx.x * 256 + tid;
    if (t >= T_DATA) return;
    float sv[20], bv[20];
    #pragma unroll
    for (int c = 0; c < 20; ++c) {
        sv[c] = b2f(spk_out[(size_t)c * T_DATA + t]);
        bv[c] = b2f(base_out[(size_t)c * T_DATA + t]);
    }
    stout(dout, (size_t)t, sv[0] + vo, mode);
    #pragma unroll
    for (int p = 0; p < 20; ++p) {
        float ps = 0.f;
        #pragma unroll
        for (int c = 0; c < 20; ++c) ps += cd[p * 20 + c] * sv[c];
        float x = bv[p] + th[p] + ps;
        float h0 = x >= 0.f ? x : 0.01f * x;
        float h1[6];
        #pragma unroll
        for (int k = 0; k < 6; ++k) {
            float y = h0 * W1[p * 6 + k];
            h1[k] = y >= 0.f ? y : 0.01f * y;
        }
        float zacc = 0.f;
        #pragma unroll
        for (int j = 0; j < 6; ++j) {
            float a = 0.f;
            #pragma unroll
            for (int k = 0; k < 6; ++k) a += h1[k] * W2[k * 6 + j];
            float h2 = a >= 0.f ? a : 0.01f * a;
            zacc += h2 * W3[j * 20 + p];
        }
        float zv = 1.f / (1.f + expf(-zacc));
        stout(dout, OFF_Z + (size_t)t * SUB + p, zv, mode);
    }
}

extern "C" void kernel_launch(void* const* d_in, const int* in_sizes, int n_in,
                              void* d_out, int out_size, void* d_ws, size_t ws_size,
                              hipStream_t stream) {
    const void* S_e     = d_in[0];
    const void* S_i     = d_in[1];
    const void* Z       = d_in[2];
    const void* C_den   = d_in[3];
    const void* C_syn_e = d_in[4];
    const void* C_syn_i = d_in[5];
    const void* W_syn   = d_in[6];
    const void* W_hist  = d_in[7];
    const void* W_spk   = d_in[8];
    const void* Delta   = d_in[9];
    const void* Tau     = d_in[10];
    const void* Vo      = d_in[11];
    const void* Theta   = d_in[12];
    const void* w1      = d_in[13];
    const void* w2      = d_in[14];
    const void* w3      = d_in[15];

    char* w = (char*)d_ws;
    int*      flag     = (int*)w;                       // 64 B slot
    float*    ws_f     = (float*)(w + 64);              // 16000 f32 filters
    int*      mape     = (int*)(w + 64 + 64000);        // 2000 int
    int*      mapi     = (int*)(w + 64 + 64000 + 8000); // 400 int
    ushort_t* sigs     = (ushort_t*)(w + 73664);        // 60 * SIGSTRIDE bf16
    ushort_t* base_out = (ushort_t*)(w + 12350144);     // [20][T] bf16
    ushort_t* spk_out  = (ushort_t*)(w + 16350144);     // [20][T] bf16 (end 20350144 B)

    hipLaunchKernelGGL(k_probe, dim3(1), dim3(64), 0, stream, Tau, flag);
    hipLaunchKernelGGL(k0_prep, dim3(158), dim3(256), 0, stream,
                       flag, C_syn_e, C_syn_i, W_syn, W_hist, W_spk, Delta, Tau,
                       ws_f, mape, mapi, sigs, d_out);
    hipLaunchKernelGGL(k1_reduce, dim3(T_DATA / TSPAN), dim3(256), 0, stream,
                       flag, S_e, S_i, Z, mape, mapi, sigs);
    hipLaunchKernelGGL(k2_conv, dim3((T_DATA + TILE - 1) / TILE, SUB), dim3(256), 0, stream,
                       sigs, ws_f, base_out, spk_out);
    hipLaunchKernelGGL(k3_mlp, dim3((T_DATA + 255) / 256), dim3(256), 0, stream,
                       flag, base_out, spk_out, C_den, Theta, Vo, w1, w2, w3, d_out);
}

// Round 5
// 290.828 us; speedup vs baseline: 1.9408x; 1.0307x over previous
//
#include <hip/hip_runtime.h>

typedef unsigned short ushort_t;
typedef unsigned int uint_t;

#define T_DATA 100000
#define E_NO 2000
#define I_NO 400
#define SUB 20
#define TNO 200
#define NBASIS 19
#define HEAD 256
#define TAILPAD 2048
#define SIGSTRIDE (HEAD + T_DATA + TAILPAD)   // 102304 bf16 per (signal, subunit)
#define TILE 2048
#define RPT 8
#define TSPAN 32                               // rows per k1 block (100000 = 3125*32)
#define ACCSTR 36                              // padded t-stride for k1 LDS acc

#define OFF_Z  ((size_t)T_DATA)                       // element offset of final_Z
#define OFF_F  ((size_t)T_DATA + (size_t)T_DATA*SUB)  // element offset of out_filters

__device__ __forceinline__ float b2f(ushort_t u) {
    union { uint_t i; float f; } v; v.i = ((uint_t)u) << 16; return v.f;
}
__device__ __forceinline__ ushort_t f2b(float f) {
    union { uint_t i; float f_; } v; v.f_ = f;
    uint_t b = v.i;
    uint_t r = (b + 0x7FFFu + ((b >> 16) & 1u)) >> 16;
    return (ushort_t)r;
}
// mode: 1 = bf16 buffers, 0 = f32 buffers
__device__ __forceinline__ float ldin(const void* p, size_t idx, int mode) {
    return mode ? b2f(((const ushort_t*)p)[idx]) : ((const float*)p)[idx];
}
__device__ __forceinline__ void stout(void* p, size_t idx, float val, int mode) {
    if (mode) ((ushort_t*)p)[idx] = f2b(val);
    else      ((float*)p)[idx] = val;
}
__device__ __forceinline__ float f4get(const float4& v, int i) {
    return i == 0 ? v.x : i == 1 ? v.y : i == 2 ? v.z : v.w;
}
__device__ __forceinline__ float pick12(const float4& L, const float4& M, const float4& H, int e) {
    return e < 4 ? f4get(L, e) : e < 8 ? f4get(M, e - 4) : f4get(H, e - 8);
}

// ---------------- probe: detect input dtype from Tau_spk (~3.0 each) ----------------
__global__ void k_probe(const void* tau, int* flag) {
    if (threadIdx.x == 0) {
        const ushort_t* tu = (const ushort_t*)tau;
        int cnt = 0;
        for (int i = 0; i < 20; ++i) {
            float v = b2f(tu[i]);
            if (v >= 1.5f && v < 6.0f) cnt++;
        }
        // bf16: all 20 in range. f32: only the 10 odd (high-half) ushorts.
        *flag = (cnt >= 15) ? 1 : 0;
    }
}

// ---------------- kernel 0: basis/filters, maps, pad zeroing ----------------
__global__ __launch_bounds__(256) void k0_prep(
        const int* __restrict__ flag,
        const void* Csyn_e, const void* Csyn_i,
        const void* W_syn, const void* W_hist,
        const void* W_spk, const void* Delta, const void* Tau,
        float* ws_f, int* mape, int* mapi, ushort_t* sigs, void* dout) {
    int mode = *flag;
    int bid = blockIdx.x, tid = threadIdx.x;
    if (bid < 80) {                       // filter rows: bid = kidx*20 + s
        int kidx = bid / 20, s = bid % 20;
        int tau = tid;
        if (tau < TNO) {
            float val;
            if (kidx < 3) {
                float raw = 5.0f * logf((float)tau + 1.0f);
                val = 0.f;
                for (int b = 0; b < NBASIS; ++b) {
                    float phi = 1.5707963267948966f * (float)b;
                    float d = raw - phi;
                    float basis = (d >= -3.14159265358979f && d <= 3.14159265358979f)
                                  ? (0.5f * cosf(d) + 0.5f) : 0.f;
                    float w = (kidx == 0) ? ldin(W_syn, (size_t)s * NBASIS * 2 + b * 2 + 0, mode)
                            : (kidx == 1) ? ldin(W_syn, (size_t)s * NBASIS * 2 + b * 2 + 1, mode)
                                          : ldin(W_hist, (size_t)s * NBASIS + b, mode);
                    val += w * basis;
                }
            } else {
                float dl = ldin(Delta, s, mode), tu = ldin(Tau, s, mode), wk = ldin(W_spk, s, mode);
                float t = fmaxf((float)tau - dl, 0.f);
                float tt = t / (tu * tu);
                val = tt * expf(-tt) * (wk * wk);
            }
            ws_f[kidx * 4000 + s * TNO + tau] = val;
            stout(dout, OFF_F + (size_t)bid * TNO + tau, val, mode);
        }
    } else if (bid < 96) {                // map_e
        int e = (bid - 80) * 256 + tid;
        if (e < E_NO) {
            int m = 0;
            for (int s = 0; s < SUB; ++s)
                if (ldin(Csyn_e, (size_t)s * E_NO + e, mode) != 0.f) { m = s; break; }
            mape[e] = m;
        }
    } else if (bid < 98) {                // map_i
        int e = (bid - 96) * 256 + tid;
        if (e < I_NO) {
            int m = 0;
            for (int s = 0; s < SUB; ++s)
                if (ldin(Csyn_i, (size_t)s * I_NO + e, mode) != 0.f) { m = s; break; }
            mapi[e] = m;
        }
    } else if (bid < 158) {               // zero head+tail pads: 60 regions
        int rg = bid - 98;                // 0..59 = sig*20 + s
        int sg = rg / 20, s = rg % 20;
        ushort_t* p = sigs + (size_t)sg * SUB * SIGSTRIDE + (size_t)s * SIGSTRIDE;
        for (int i = tid; i < HEAD; i += 256) p[i] = 0;
        for (int i = tid; i < TAILPAD; i += 256) p[HEAD + T_DATA + i] = 0;
    }
}

// ---------------- kernel 1 v4: 32-row span, x4-batched loads, hoisted buckets ----------
// Block owns rows [base, base+32). Per 4-row group: all loads issued first
// (4 uint4 in flight per thread), then decode + sparse LDS atomics. Bucket
// indices me[tid*8+j]/mi[...] hoisted to registers (loop-invariant). One
// barrier, then coalesced packed-bf16 writes (64B aligned run per sig row).
__global__ __launch_bounds__(256) void k1_reduce(
        const int* __restrict__ flag,
        const void* __restrict__ S_e, const void* __restrict__ S_i,
        const void* __restrict__ Z,
        const int* __restrict__ mape, const int* __restrict__ mapi,
        ushort_t* __restrict__ sigs) {
    __shared__ float acc[60 * ACCSTR];
    int tid = threadIdx.x;
    int mode = *flag;
    for (int i = tid; i < 60 * ACCSTR; i += 256) acc[i] = 0.f;

    // hoist bucket indices to registers (loop-invariant per thread)
    int be[8], bi8[8];
    if (mode) {
        if (tid < 250) {
            #pragma unroll
            for (int j = 0; j < 8; ++j) be[j] = mape[tid * 8 + j] * ACCSTR;
        }
        if (tid < 50) {
            #pragma unroll
            for (int j = 0; j < 8; ++j) bi8[j] = (20 + mapi[tid * 8 + j]) * ACCSTR;
        }
    } else {
        if (tid < 250) {
            #pragma unroll
            for (int j = 0; j < 4; ++j) be[j] = mape[tid * 4 + j] * ACCSTR;
            #pragma unroll
            for (int j = 0; j < 4; ++j) be[4 + j] = mape[(tid + 250) * 4 + j] * ACCSTR;
        }
        if (tid < 100) {
            #pragma unroll
            for (int j = 0; j < 4; ++j) bi8[j] = (20 + mapi[tid * 4 + j]) * ACCSTR;
        }
    }
    __syncthreads();

    int base = blockIdx.x * TSPAN;
    if (mode) {
        for (int r0 = 0; r0 < TSPAN; r0 += 4) {
            uint4 u[4];
            uint4 w[4];
            float zv[4];
            if (tid < 250) {
                #pragma unroll
                for (int k = 0; k < 4; ++k)
                    u[k] = *(const uint4*)((const ushort_t*)S_e +
                                           (size_t)(base + r0 + k) * E_NO + tid * 8);
            }
            if (tid < 50) {
                #pragma unroll
                for (int k = 0; k < 4; ++k)
                    w[k] = *(const uint4*)((const ushort_t*)S_i +
                                           (size_t)(base + r0 + k) * I_NO + tid * 8);
            }
            if (tid >= 192 && tid < 212) {
                int s = tid - 192;
                #pragma unroll
                for (int k = 0; k < 4; ++k)
                    zv[k] = b2f(((const ushort_t*)Z)[(size_t)(base + r0 + k) * SUB + s]);
            }
            if (tid < 250) {
                #pragma unroll
                for (int k = 0; k < 4; ++k) {
                    int rl = r0 + k;
                    uint_t wd[4] = {u[k].x, u[k].y, u[k].z, u[k].w};
                    #pragma unroll
                    for (int q = 0; q < 4; ++q) {
                        float a = b2f((ushort_t)(wd[q] & 0xFFFF));
                        float b = b2f((ushort_t)(wd[q] >> 16));
                        if (a != 0.f) atomicAdd(&acc[be[2 * q] + rl], a);
                        if (b != 0.f) atomicAdd(&acc[be[2 * q + 1] + rl], b);
                    }
                }
            }
            if (tid < 50) {
                #pragma unroll
                for (int k = 0; k < 4; ++k) {
                    int rl = r0 + k;
                    uint_t wd[4] = {w[k].x, w[k].y, w[k].z, w[k].w};
                    #pragma unroll
                    for (int q = 0; q < 4; ++q) {
                        float a = b2f((ushort_t)(wd[q] & 0xFFFF));
                        float b = b2f((ushort_t)(wd[q] >> 16));
                        if (a != 0.f) atomicAdd(&acc[bi8[2 * q] + rl], a);
                        if (b != 0.f) atomicAdd(&acc[bi8[2 * q + 1] + rl], b);
                    }
                }
            }
            if (tid >= 192 && tid < 212) {
                int s = tid - 192;
                #pragma unroll
                for (int k = 0; k < 4; ++k)
                    acc[(40 + s) * ACCSTR + r0 + k] = zv[k];
            }
        }
    } else {
        for (int r0 = 0; r0 < TSPAN; r0 += 2) {
            float4 u[4];
            float4 w[2];
            float zv[2];
            if (tid < 250) {
                #pragma unroll
                for (int k = 0; k < 2; ++k) {
                    const float* pe = (const float*)S_e + (size_t)(base + r0 + k) * E_NO;
                    u[2 * k]     = *(const float4*)(pe + tid * 4);
                    u[2 * k + 1] = *(const float4*)(pe + (tid + 250) * 4);
                }
            }
            if (tid < 100) {
                #pragma unroll
                for (int k = 0; k < 2; ++k)
                    w[k] = *(const float4*)((const float*)S_i +
                                            (size_t)(base + r0 + k) * I_NO + tid * 4);
            }
            if (tid >= 192 && tid < 212) {
                int s = tid - 192;
                #pragma unroll
                for (int k = 0; k < 2; ++k)
                    zv[k] = ((const float*)Z)[(size_t)(base + r0 + k) * SUB + s];
            }
            if (tid < 250) {
                #pragma unroll
                for (int k = 0; k < 2; ++k) {
                    int rl = r0 + k;
                    float v0[4] = {u[2*k].x, u[2*k].y, u[2*k].z, u[2*k].w};
                    float v1[4] = {u[2*k+1].x, u[2*k+1].y, u[2*k+1].z, u[2*k+1].w};
                    #pragma unroll
                    for (int q = 0; q < 4; ++q) {
                        if (v0[q] != 0.f) atomicAdd(&acc[be[q] + rl], v0[q]);
                        if (v1[q] != 0.f) atomicAdd(&acc[be[4 + q] + rl], v1[q]);
                    }
                }
            }
            if (tid < 100) {
                #pragma unroll
                for (int k = 0; k < 2; ++k) {
                    int rl = r0 + k;
                    float v[4] = {w[k].x, w[k].y, w[k].z, w[k].w};
                    #pragma unroll
                    for (int q = 0; q < 4; ++q)
                        if (v[q] != 0.f) atomicAdd(&acc[bi8[q] + rl], v[q]);
                }
            }
            if (tid >= 192 && tid < 212) {
                int s = tid - 192;
                #pragma unroll
                for (int k = 0; k < 2; ++k)
                    acc[(40 + s) * ACCSTR + r0 + k] = zv[k];
            }
        }
    }
    __syncthreads();

    // Phase B: 60 signal rows x 32 t, packed bf16, 4 t per uint2 store.
    // 8 consecutive threads cover one sig row's 64B aligned run.
    for (int idx = tid; idx < 60 * (TSPAN / 4); idx += 256) {
        int sig = idx >> 3;                // / 8
        int g = idx & 7;
        int t0 = g * 4;
        const float* src = &acc[sig * ACCSTR + t0];
        float4 v = *(const float4*)src;
        uint2 o;
        o.x = (uint_t)f2b(v.x) | ((uint_t)f2b(v.y) << 16);
        o.y = (uint_t)f2b(v.z) | ((uint_t)f2b(v.w) << 16);
        *(uint2*)(sigs + (size_t)sig * SIGSTRIDE + HEAD + base + t0) = o;
    }
}

// ---------------- kernel 2: 4x 200-tap depthwise FIR, f32 accum ----------------
__global__ __launch_bounds__(256) void k2_conv(
        const ushort_t* __restrict__ sigs, const float* __restrict__ ws_f,
        ushort_t* __restrict__ base_out, ushort_t* __restrict__ spk_out) {
    __shared__ float X[3 * 2248 + 800];
    float* XE = X;
    float* XI = X + 2248;
    float* ZZ = X + 4496;
    float* KK = X + 6744;
    int s = blockIdx.y;
    int t0 = blockIdx.x * TILE;
    int tid = threadIdx.x;

    for (int k = 0; k < 4; ++k)
        for (int j = tid; j < TNO; j += 256)
            KK[k * TNO + j] = ws_f[k * 4000 + s * TNO + j];

    {
        const ushort_t* g0 = sigs + (size_t)s * SIGSTRIDE + (HEAD - 200) + t0;
        const ushort_t* g1 = g0 + (size_t)SUB * SIGSTRIDE;
        const ushort_t* g2 = g0 + (size_t)2 * SUB * SIGSTRIDE;
        for (int v = tid; v < 281; v += 256) {
            uint4 u = *(const uint4*)(g0 + v * 8);
            float* d = XE + v * 8;
            d[0]=b2f((ushort_t)(u.x&0xFFFF)); d[1]=b2f((ushort_t)(u.x>>16));
            d[2]=b2f((ushort_t)(u.y&0xFFFF)); d[3]=b2f((ushort_t)(u.y>>16));
            d[4]=b2f((ushort_t)(u.z&0xFFFF)); d[5]=b2f((ushort_t)(u.z>>16));
            d[6]=b2f((ushort_t)(u.w&0xFFFF)); d[7]=b2f((ushort_t)(u.w>>16));
        }
        for (int v = tid; v < 281; v += 256) {
            uint4 u = *(const uint4*)(g1 + v * 8);
            float* d = XI + v * 8;
            d[0]=b2f((ushort_t)(u.x&0xFFFF)); d[1]=b2f((ushort_t)(u.x>>16));
            d[2]=b2f((ushort_t)(u.y&0xFFFF)); d[3]=b2f((ushort_t)(u.y>>16));
            d[4]=b2f((ushort_t)(u.z&0xFFFF)); d[5]=b2f((ushort_t)(u.z>>16));
            d[6]=b2f((ushort_t)(u.w&0xFFFF)); d[7]=b2f((ushort_t)(u.w>>16));
        }
        for (int v = tid; v < 281; v += 256) {
            uint4 u = *(const uint4*)(g2 + v * 8);
            float* d = ZZ + v * 8;
            d[0]=b2f((ushort_t)(u.x&0xFFFF)); d[1]=b2f((ushort_t)(u.x>>16));
            d[2]=b2f((ushort_t)(u.y&0xFFFF)); d[3]=b2f((ushort_t)(u.y>>16));
            d[4]=b2f((ushort_t)(u.z&0xFFFF)); d[5]=b2f((ushort_t)(u.z>>16));
            d[6]=b2f((ushort_t)(u.w&0xFFFF)); d[7]=b2f((ushort_t)(u.w>>16));
        }
    }
    __syncthreads();

    float acc[RPT] = {0,0,0,0,0,0,0,0};
    float spk[RPT] = {0,0,0,0,0,0,0,0};
    const float4* XE4 = (const float4*)XE;
    const float4* XI4 = (const float4*)XI;
    const float4* ZZ4 = (const float4*)ZZ;
    const float4* KE4 = (const float4*)(KK);
    const float4* KI4 = (const float4*)(KK + 200);
    const float4* KH4 = (const float4*)(KK + 400);
    const float4* KS4 = (const float4*)(KK + 600);
    int w4 = 2 * tid + 49;                 // float4 index of window base W = 8*tid+196
    float4 eL = XE4[w4], eM = XE4[w4 + 1], eH = XE4[w4 + 2];
    float4 iL = XI4[w4], iM = XI4[w4 + 1], iH = XI4[w4 + 2];
    float4 zL = ZZ4[w4], zM = ZZ4[w4 + 1], zH = ZZ4[w4 + 2];

    for (int c = 0; c < 50; ++c) {
        if (c > 0) {
            eH = eM; eM = eL; eL = XE4[w4 - c];
            iH = iM; iM = iL; iL = XI4[w4 - c];
            zH = zM; zM = zL; zL = ZZ4[w4 - c];
        }
        float4 ke = KE4[c], ki = KI4[c], kh = KH4[c], ks = KS4[c];
        #pragma unroll
        for (int u = 0; u < 4; ++u) {
            float keu = f4get(ke, u), kiu = f4get(ki, u);
            float khu = f4get(kh, u), ksu = f4get(ks, u);
            #pragma unroll
            for (int r = 0; r < RPT; ++r) {
                float xe = pick12(eL, eM, eH, 4 + r - u);
                float xi = pick12(iL, iM, iH, 4 + r - u);
                float zz = pick12(zL, zM, zH, 3 + r - u);
                acc[r] += keu * xe;
                acc[r] += kiu * xi;
                acc[r] += khu * zz;
                spk[r] += ksu * zz;
            }
        }
    }
    int tbase = t0 + RPT * tid;
    if (tbase + RPT <= T_DATA) {
        uint4 pb, pq;
        pb.x = (uint_t)f2b(acc[0]) | ((uint_t)f2b(acc[1]) << 16);
        pb.y = (uint_t)f2b(acc[2]) | ((uint_t)f2b(acc[3]) << 16);
        pb.z = (uint_t)f2b(acc[4]) | ((uint_t)f2b(acc[5]) << 16);
        pb.w = (uint_t)f2b(acc[6]) | ((uint_t)f2b(acc[7]) << 16);
        pq.x = (uint_t)f2b(spk[0]) | ((uint_t)f2b(spk[1]) << 16);
        pq.y = (uint_t)f2b(spk[2]) | ((uint_t)f2b(spk[3]) << 16);
        pq.z = (uint_t)f2b(spk[4]) | ((uint_t)f2b(spk[5]) << 16);
        pq.w = (uint_t)f2b(spk[6]) | ((uint_t)f2b(spk[7]) << 16);
        *(uint4*)(base_out + (size_t)s * T_DATA + tbase) = pb;
        *(uint4*)(spk_out + (size_t)s * T_DATA + tbase) = pq;
    } else {
        #pragma unroll
        for (int r = 0; r < RPT; ++r) {
            int t = tbase + r;
            if (t < T_DATA) {
                base_out[(size_t)s * T_DATA + t] = f2b(acc[r]);
                spk_out[(size_t)s * T_DATA + t] = f2b(spk[r]);
            }
        }
    }
}

// ---------------- kernel 3: tree gather + MLP + outputs ----------------
__global__ __launch_bounds__(256) void k3_mlp(
        const int* __restrict__ flag,
        const ushort_t* __restrict__ base_out, const ushort_t* __restrict__ spk_out,
        const void* __restrict__ C_den, const void* __restrict__ Theta,
        const void* __restrict__ Vo,
        const void* __restrict__ w1, const void* __restrict__ w2,
        const void* __restrict__ w3,
        void* __restrict__ dout) {
    __shared__ float cd[400], th[20], W1[120], W2[36], W3[120];
    __shared__ float vo;
    int tid = threadIdx.x;
    int mode = *flag;
    for (int i = tid; i < 400; i += 256) cd[i] = ldin(C_den, i, mode);
    if (tid < 20) th[tid] = ldin(Theta, tid, mode);
    if (tid < 120) W1[tid] = ldin(w1, tid, mode);
    if (tid < 36) W2[tid] = ldin(w2, tid, mode);
    if (tid >= 128 && tid < 248) W3[tid - 128] = ldin(w3, tid - 128, mode);
    if (tid == 0) vo = ldin(Vo, 0, mode);
    __syncthreads();
    int t = blockIdx.x * 256 + tid;
    if (t >= T_DATA) return;
    float sv[20], bv[20];
    #pragma unroll
    for (int c = 0; c < 20; ++c) {
        sv[c] = b2f(spk_out[(size_t)c * T_DATA + t]);
        bv[c] = b2f(base_out[(size_t)c * T_DATA + t]);
    }
    stout(dout, (size_t)t, sv[0] + vo, mode);
    #pragma unroll
    for (int p = 0; p < 20; ++p) {
        float ps = 0.f;
        #pragma unroll
        for (int c = 0; c < 20; ++c) ps += cd[p * 20 + c] * sv[c];
        float x = bv[p] + th[p] + ps;
        float h0 = x >= 0.f ? x : 0.01f * x;
        float h1[6];
        #pragma unroll
        for (int k = 0; k < 6; ++k) {
            float y = h0 * W1[p * 6 + k];
            h1[k] = y >= 0.f ? y : 0.01f * y;
        }
        float zacc = 0.f;
        #pragma unroll
        for (int j = 0; j < 6; ++j) {
            float a = 0.f;
            #pragma unroll
            for (int k = 0; k < 6; ++k) a += h1[k] * W2[k * 6 + j];
            float h2 = a >= 0.f ? a : 0.01f * a;
            zacc += h2 * W3[j * 20 + p];
        }
        float zv = 1.f / (1.f + expf(-zacc));
        stout(dout, OFF_Z + (size_t)t * SUB + p, zv, mode);
    }
}

extern "C" void kernel_launch(void* const* d_in, const int* in_sizes, int n_in,
                              void* d_out, int out_size, void* d_ws, size_t ws_size,
                              hipStream_t stream) {
    const void* S_e     = d_in[0];
    const void* S_i     = d_in[1];
    const void* Z       = d_in[2];
    const void* C_den   = d_in[3];
    const void* C_syn_e = d_in[4];
    const void* C_syn_i = d_in[5];
    const void* W_syn   = d_in[6];
    const void* W_hist  = d_in[7];
    const void* W_spk   = d_in[8];
    const void* Delta   = d_in[9];
    const void* Tau     = d_in[10];
    const void* Vo      = d_in[11];
    const void* Theta   = d_in[12];
    const void* w1      = d_in[13];
    const void* w2      = d_in[14];
    const void* w3      = d_in[15];

    char* w = (char*)d_ws;
    int*      flag     = (int*)w;                       // 64 B slot
    float*    ws_f     = (float*)(w + 64);              // 16000 f32 filters
    int*      mape     = (int*)(w + 64 + 64000);        // 2000 int
    int*      mapi     = (int*)(w + 64 + 64000 + 8000); // 400 int
    ushort_t* sigs     = (ushort_t*)(w + 73664);        // 60 * SIGSTRIDE bf16
    ushort_t* base_out = (ushort_t*)(w + 12350144);     // [20][T] bf16
    ushort_t* spk_out  = (ushort_t*)(w + 16350144);     // [20][T] bf16 (end 20350144 B)

    hipLaunchKernelGGL(k_probe, dim3(1), dim3(64), 0, stream, Tau, flag);
    hipLaunchKernelGGL(k0_prep, dim3(158), dim3(256), 0, stream,
                       flag, C_syn_e, C_syn_i, W_syn, W_hist, W_spk, Delta, Tau,
                       ws_f, mape, mapi, sigs, d_out);
    hipLaunchKernelGGL(k1_reduce, dim3(T_DATA / TSPAN), dim3(256), 0, stream,
                       flag, S_e, S_i, Z, mape, mapi, sigs);
    hipLaunchKernelGGL(k2_conv, dim3((T_DATA + TILE - 1) / TILE, SUB), dim3(256), 0, stream,
                       sigs, ws_f, base_out, spk_out);
    hipLaunchKernelGGL(k3_mlp, dim3((T_DATA + 255) / 256), dim3(256), 0, stream,
                       flag, base_out, spk_out, C_den, Theta, Vo, w1, w2, w3, d_out);
}

// Round 6
// 271.684 us; speedup vs baseline: 2.0776x; 1.0705x over previous
//
#include <hip/hip_runtime.h>

typedef unsigned short ushort_t;
typedef unsigned int uint_t;
typedef float __attribute__((ext_vector_type(4))) f32x4;

#define T_DATA 100000
#define E_NO 2000
#define I_NO 400
#define SUB 20
#define TNO 200
#define NBASIS 19
#define HEAD 256
#define TAILPAD 2048
#define SIGSTRIDE (HEAD + T_DATA + TAILPAD)   // 102304 bf16 per (signal, subunit)
#define TILE 2048
#define RPT 8
#define TSPAN 32                               // rows per k1 block (100000 = 3125*32)
#define ACCSTR 36                              // padded t-stride for k1 LDS acc

#define OFF_Z  ((size_t)T_DATA)                       // element offset of final_Z
#define OFF_F  ((size_t)T_DATA + (size_t)T_DATA*SUB)  // element offset of out_filters

__device__ __forceinline__ float b2f(ushort_t u) {
    union { uint_t i; float f; } v; v.i = ((uint_t)u) << 16; return v.f;
}
__device__ __forceinline__ ushort_t f2b(float f) {
    union { uint_t i; float f_; } v; v.f_ = f;
    uint_t b = v.i;
    uint_t r = (b + 0x7FFFu + ((b >> 16) & 1u)) >> 16;
    return (ushort_t)r;
}
// mode: 1 = bf16 buffers, 0 = f32 buffers
__device__ __forceinline__ float ldin(const void* p, size_t idx, int mode) {
    return mode ? b2f(((const ushort_t*)p)[idx]) : ((const float*)p)[idx];
}
__device__ __forceinline__ void stout(void* p, size_t idx, float val, int mode) {
    if (mode) ((ushort_t*)p)[idx] = f2b(val);
    else      ((float*)p)[idx] = val;
}
__device__ __forceinline__ float f4get(const float4& v, int i) {
    return i == 0 ? v.x : i == 1 ? v.y : i == 2 ? v.z : v.w;
}
__device__ __forceinline__ float pick12(const float4& L, const float4& M, const float4& H, int e) {
    return e < 4 ? f4get(L, e) : e < 8 ? f4get(M, e - 4) : f4get(H, e - 8);
}
// dtype probe: Tau_spk ~3.0 each. bf16: all 20 ushorts decode to [1.5,6);
// f32: only the 10 odd (high-half) ushorts do.
__device__ __forceinline__ int detect_mode(const void* tau) {
    const ushort_t* tu = (const ushort_t*)tau;
    int cnt = 0;
    #pragma unroll
    for (int i = 0; i < 20; ++i) {
        float v = b2f(tu[i]);
        if (v >= 1.5f && v < 6.0f) cnt++;
    }
    return (cnt >= 15) ? 1 : 0;
}

// ---------------- kernel 0: basis/filters, maps, pad zeroing ----------------
__global__ __launch_bounds__(256) void k0_prep(
        const void* Csyn_e, const void* Csyn_i,
        const void* W_syn, const void* W_hist,
        const void* W_spk, const void* Delta, const void* Tau,
        float* ws_f, int* mape, int* mapi, ushort_t* sigs, void* dout) {
    __shared__ int smode;
    int bid = blockIdx.x, tid = threadIdx.x;
    if (tid == 0) smode = detect_mode(Tau);
    __syncthreads();
    int mode = smode;
    if (bid < 80) {                       // filter rows: bid = kidx*20 + s
        int kidx = bid / 20, s = bid % 20;
        int tau = tid;
        if (tau < TNO) {
            float val;
            if (kidx < 3) {
                float raw = 5.0f * logf((float)tau + 1.0f);
                val = 0.f;
                for (int b = 0; b < NBASIS; ++b) {
                    float phi = 1.5707963267948966f * (float)b;
                    float d = raw - phi;
                    float basis = (d >= -3.14159265358979f && d <= 3.14159265358979f)
                                  ? (0.5f * cosf(d) + 0.5f) : 0.f;
                    float w = (kidx == 0) ? ldin(W_syn, (size_t)s * NBASIS * 2 + b * 2 + 0, mode)
                            : (kidx == 1) ? ldin(W_syn, (size_t)s * NBASIS * 2 + b * 2 + 1, mode)
                                          : ldin(W_hist, (size_t)s * NBASIS + b, mode);
                    val += w * basis;
                }
            } else {
                float dl = ldin(Delta, s, mode), tu = ldin(Tau, s, mode), wk = ldin(W_spk, s, mode);
                float t = fmaxf((float)tau - dl, 0.f);
                float tt = t / (tu * tu);
                val = tt * expf(-tt) * (wk * wk);
            }
            ws_f[kidx * 4000 + s * TNO + tau] = val;
            stout(dout, OFF_F + (size_t)bid * TNO + tau, val, mode);
        }
    } else if (bid < 96) {                // map_e
        int e = (bid - 80) * 256 + tid;
        if (e < E_NO) {
            int m = 0;
            for (int s = 0; s < SUB; ++s)
                if (ldin(Csyn_e, (size_t)s * E_NO + e, mode) != 0.f) { m = s; break; }
            mape[e] = m;
        }
    } else if (bid < 98) {                // map_i
        int e = (bid - 96) * 256 + tid;
        if (e < I_NO) {
            int m = 0;
            for (int s = 0; s < SUB; ++s)
                if (ldin(Csyn_i, (size_t)s * I_NO + e, mode) != 0.f) { m = s; break; }
            mapi[e] = m;
        }
    } else if (bid < 158) {               // zero head+tail pads: 60 regions
        int rg = bid - 98;                // 0..59 = sig*20 + s
        int sg = rg / 20, s = rg % 20;
        ushort_t* p = sigs + (size_t)sg * SUB * SIGSTRIDE + (size_t)s * SIGSTRIDE;
        for (int i = tid; i < HEAD; i += 256) p[i] = 0;
        for (int i = tid; i < TAILPAD; i += 256) p[HEAD + T_DATA + i] = 0;
    }
}

// ---------------- kernel 1 v5: 32-row span, 4-row-deep load batching, nt loads ----------
// Block owns rows [base, base+32). Per 4-row group: ALL global loads issued
// back-to-back (8 S_e float4 + 4 S_i float4 per thread in flight), then decode
// + sparse LDS atomics. Bucket indices hoisted to registers. One barrier, then
// coalesced packed-bf16 writes (64B aligned run per sig row).
__global__ __launch_bounds__(256, 4) void k1_reduce(
        const void* __restrict__ S_e, const void* __restrict__ S_i,
        const void* __restrict__ Z,
        const int* __restrict__ mape, const int* __restrict__ mapi,
        const void* __restrict__ Tau,
        ushort_t* __restrict__ sigs) {
    __shared__ float acc[60 * ACCSTR];
    __shared__ int smode;
    int tid = threadIdx.x;
    if (tid == 0) smode = detect_mode(Tau);
    for (int i = tid; i < 60 * ACCSTR; i += 256) acc[i] = 0.f;
    __syncthreads();
    int mode = smode;

    // hoist bucket indices to registers (loop-invariant per thread)
    int be[8], bi8[8];
    if (mode) {
        if (tid < 250) {
            #pragma unroll
            for (int j = 0; j < 8; ++j) be[j] = mape[tid * 8 + j] * ACCSTR;
        }
        if (tid < 50) {
            #pragma unroll
            for (int j = 0; j < 8; ++j) bi8[j] = (20 + mapi[tid * 8 + j]) * ACCSTR;
        }
    } else {
        if (tid < 250) {
            #pragma unroll
            for (int j = 0; j < 4; ++j) be[j] = mape[tid * 4 + j] * ACCSTR;
            #pragma unroll
            for (int j = 0; j < 4; ++j) be[4 + j] = mape[(tid + 250) * 4 + j] * ACCSTR;
        }
        if (tid < 100) {
            #pragma unroll
            for (int j = 0; j < 4; ++j) bi8[j] = (20 + mapi[tid * 4 + j]) * ACCSTR;
        }
    }

    int base = blockIdx.x * TSPAN;
    if (mode) {
        for (int r0 = 0; r0 < TSPAN; r0 += 4) {
            uint4 u[4];
            uint4 w[4];
            float zv[4];
            if (tid < 250) {
                #pragma unroll
                for (int k = 0; k < 4; ++k)
                    u[k] = *(const uint4*)((const ushort_t*)S_e +
                                           (size_t)(base + r0 + k) * E_NO + tid * 8);
            }
            if (tid < 50) {
                #pragma unroll
                for (int k = 0; k < 4; ++k)
                    w[k] = *(const uint4*)((const ushort_t*)S_i +
                                           (size_t)(base + r0 + k) * I_NO + tid * 8);
            }
            if (tid >= 192 && tid < 212) {
                int s = tid - 192;
                #pragma unroll
                for (int k = 0; k < 4; ++k)
                    zv[k] = b2f(((const ushort_t*)Z)[(size_t)(base + r0 + k) * SUB + s]);
            }
            if (tid < 250) {
                #pragma unroll
                for (int k = 0; k < 4; ++k) {
                    int rl = r0 + k;
                    uint_t wd[4] = {u[k].x, u[k].y, u[k].z, u[k].w};
                    #pragma unroll
                    for (int q = 0; q < 4; ++q) {
                        float a = b2f((ushort_t)(wd[q] & 0xFFFF));
                        float b = b2f((ushort_t)(wd[q] >> 16));
                        if (a != 0.f) atomicAdd(&acc[be[2 * q] + rl], a);
                        if (b != 0.f) atomicAdd(&acc[be[2 * q + 1] + rl], b);
                    }
                }
            }
            if (tid < 50) {
                #pragma unroll
                for (int k = 0; k < 4; ++k) {
                    int rl = r0 + k;
                    uint_t wd[4] = {w[k].x, w[k].y, w[k].z, w[k].w};
                    #pragma unroll
                    for (int q = 0; q < 4; ++q) {
                        float a = b2f((ushort_t)(wd[q] & 0xFFFF));
                        float b = b2f((ushort_t)(wd[q] >> 16));
                        if (a != 0.f) atomicAdd(&acc[bi8[2 * q] + rl], a);
                        if (b != 0.f) atomicAdd(&acc[bi8[2 * q + 1] + rl], b);
                    }
                }
            }
            if (tid >= 192 && tid < 212) {
                int s = tid - 192;
                #pragma unroll
                for (int k = 0; k < 4; ++k)
                    acc[(40 + s) * ACCSTR + r0 + k] = zv[k];
            }
        }
    } else {
        for (int r0 = 0; r0 < TSPAN; r0 += 4) {
            f32x4 u[8];
            f32x4 w[4];
            float zv[4];
            if (tid < 250) {
                #pragma unroll
                for (int k = 0; k < 4; ++k) {
                    const float* pe = (const float*)S_e + (size_t)(base + r0 + k) * E_NO;
                    u[2 * k]     = __builtin_nontemporal_load((const f32x4*)(pe + tid * 4));
                    u[2 * k + 1] = __builtin_nontemporal_load((const f32x4*)(pe + (tid + 250) * 4));
                }
            }
            if (tid < 100) {
                #pragma unroll
                for (int k = 0; k < 4; ++k)
                    w[k] = __builtin_nontemporal_load(
                        (const f32x4*)((const float*)S_i + (size_t)(base + r0 + k) * I_NO + tid * 4));
            }
            if (tid >= 192 && tid < 212) {
                int s = tid - 192;
                #pragma unroll
                for (int k = 0; k < 4; ++k)
                    zv[k] = ((const float*)Z)[(size_t)(base + r0 + k) * SUB + s];
            }
            if (tid < 250) {
                #pragma unroll
                for (int k = 0; k < 4; ++k) {
                    int rl = r0 + k;
                    #pragma unroll
                    for (int q = 0; q < 4; ++q) {
                        float a = u[2 * k][q];
                        float b = u[2 * k + 1][q];
                        if (a != 0.f) atomicAdd(&acc[be[q] + rl], a);
                        if (b != 0.f) atomicAdd(&acc[be[4 + q] + rl], b);
                    }
                }
            }
            if (tid < 100) {
                #pragma unroll
                for (int k = 0; k < 4; ++k) {
                    int rl = r0 + k;
                    #pragma unroll
                    for (int q = 0; q < 4; ++q) {
                        float c = w[k][q];
                        if (c != 0.f) atomicAdd(&acc[bi8[q] + rl], c);
                    }
                }
            }
            if (tid >= 192 && tid < 212) {
                int s = tid - 192;
                #pragma unroll
                for (int k = 0; k < 4; ++k)
                    acc[(40 + s) * ACCSTR + r0 + k] = zv[k];
            }
        }
    }
    __syncthreads();

    // Phase B: 60 signal rows x 32 t, packed bf16, 4 t per uint2 store.
    // 8 consecutive threads cover one sig row's 64B aligned run.
    for (int idx = tid; idx < 60 * (TSPAN / 4); idx += 256) {
        int sig = idx >> 3;                // / 8
        int g = idx & 7;
        int t0 = g * 4;
        const float* src = &acc[sig * ACCSTR + t0];
        float4 v = *(const float4*)src;
        uint2 o;
        o.x = (uint_t)f2b(v.x) | ((uint_t)f2b(v.y) << 16);
        o.y = (uint_t)f2b(v.z) | ((uint_t)f2b(v.w) << 16);
        *(uint2*)(sigs + (size_t)sig * SIGSTRIDE + HEAD + base + t0) = o;
    }
}

// ---------------- kernel 2: 4x 200-tap depthwise FIR, f32 accum ----------------
__global__ __launch_bounds__(256) void k2_conv(
        const ushort_t* __restrict__ sigs, const float* __restrict__ ws_f,
        ushort_t* __restrict__ base_out, ushort_t* __restrict__ spk_out) {
    __shared__ float X[3 * 2248 + 800];
    float* XE = X;
    float* XI = X + 2248;
    float* ZZ = X + 4496;
    float* KK = X + 6744;
    int s = blockIdx.y;
    int t0 = blockIdx.x * TILE;
    int tid = threadIdx.x;

    for (int k = 0; k < 4; ++k)
        for (int j = tid; j < TNO; j += 256)
            KK[k * TNO + j] = ws_f[k * 4000 + s * TNO + j];

    {
        const ushort_t* g0 = sigs + (size_t)s * SIGSTRIDE + (HEAD - 200) + t0;
        const ushort_t* g1 = g0 + (size_t)SUB * SIGSTRIDE;
        const ushort_t* g2 = g0 + (size_t)2 * SUB * SIGSTRIDE;
        for (int v = tid; v < 281; v += 256) {
            uint4 u = *(const uint4*)(g0 + v * 8);
            float* d = XE + v * 8;
            d[0]=b2f((ushort_t)(u.x&0xFFFF)); d[1]=b2f((ushort_t)(u.x>>16));
            d[2]=b2f((ushort_t)(u.y&0xFFFF)); d[3]=b2f((ushort_t)(u.y>>16));
            d[4]=b2f((ushort_t)(u.z&0xFFFF)); d[5]=b2f((ushort_t)(u.z>>16));
            d[6]=b2f((ushort_t)(u.w&0xFFFF)); d[7]=b2f((ushort_t)(u.w>>16));
        }
        for (int v = tid; v < 281; v += 256) {
            uint4 u = *(const uint4*)(g1 + v * 8);
            float* d = XI + v * 8;
            d[0]=b2f((ushort_t)(u.x&0xFFFF)); d[1]=b2f((ushort_t)(u.x>>16));
            d[2]=b2f((ushort_t)(u.y&0xFFFF)); d[3]=b2f((ushort_t)(u.y>>16));
            d[4]=b2f((ushort_t)(u.z&0xFFFF)); d[5]=b2f((ushort_t)(u.z>>16));
            d[6]=b2f((ushort_t)(u.w&0xFFFF)); d[7]=b2f((ushort_t)(u.w>>16));
        }
        for (int v = tid; v < 281; v += 256) {
            uint4 u = *(const uint4*)(g2 + v * 8);
            float* d = ZZ + v * 8;
            d[0]=b2f((ushort_t)(u.x&0xFFFF)); d[1]=b2f((ushort_t)(u.x>>16));
            d[2]=b2f((ushort_t)(u.y&0xFFFF)); d[3]=b2f((ushort_t)(u.y>>16));
            d[4]=b2f((ushort_t)(u.z&0xFFFF)); d[5]=b2f((ushort_t)(u.z>>16));
            d[6]=b2f((ushort_t)(u.w&0xFFFF)); d[7]=b2f((ushort_t)(u.w>>16));
        }
    }
    __syncthreads();

    float acc[RPT] = {0,0,0,0,0,0,0,0};
    float spk[RPT] = {0,0,0,0,0,0,0,0};
    const float4* XE4 = (const float4*)XE;
    const float4* XI4 = (const float4*)XI;
    const float4* ZZ4 = (const float4*)ZZ;
    const float4* KE4 = (const float4*)(KK);
    const float4* KI4 = (const float4*)(KK + 200);
    const float4* KH4 = (const float4*)(KK + 400);
    const float4* KS4 = (const float4*)(KK + 600);
    int w4 = 2 * tid + 49;                 // float4 index of window base W = 8*tid+196
    float4 eL = XE4[w4], eM = XE4[w4 + 1], eH = XE4[w4 + 2];
    float4 iL = XI4[w4], iM = XI4[w4 + 1], iH = XI4[w4 + 2];
    float4 zL = ZZ4[w4], zM = ZZ4[w4 + 1], zH = ZZ4[w4 + 2];

    for (int c = 0; c < 50; ++c) {
        if (c > 0) {
            eH = eM; eM = eL; eL = XE4[w4 - c];
            iH = iM; iM = iL; iL = XI4[w4 - c];
            zH = zM; zM = zL; zL = ZZ4[w4 - c];
        }
        float4 ke = KE4[c], ki = KI4[c], kh = KH4[c], ks = KS4[c];
        #pragma unroll
        for (int u = 0; u < 4; ++u) {
            float keu = f4get(ke, u), kiu = f4get(ki, u);
            float khu = f4get(kh, u), ksu = f4get(ks, u);
            #pragma unroll
            for (int r = 0; r < RPT; ++r) {
                float xe = pick12(eL, eM, eH, 4 + r - u);
                float xi = pick12(iL, iM, iH, 4 + r - u);
                float zz = pick12(zL, zM, zH, 3 + r - u);
                acc[r] += keu * xe;
                acc[r] += kiu * xi;
                acc[r] += khu * zz;
                spk[r] += ksu * zz;
            }
        }
    }
    int tbase = t0 + RPT * tid;
    if (tbase + RPT <= T_DATA) {
        uint4 pb, pq;
        pb.x = (uint_t)f2b(acc[0]) | ((uint_t)f2b(acc[1]) << 16);
        pb.y = (uint_t)f2b(acc[2]) | ((uint_t)f2b(acc[3]) << 16);
        pb.z = (uint_t)f2b(acc[4]) | ((uint_t)f2b(acc[5]) << 16);
        pb.w = (uint_t)f2b(acc[6]) | ((uint_t)f2b(acc[7]) << 16);
        pq.x = (uint_t)f2b(spk[0]) | ((uint_t)f2b(spk[1]) << 16);
        pq.y = (uint_t)f2b(spk[2]) | ((uint_t)f2b(spk[3]) << 16);
        pq.z = (uint_t)f2b(spk[4]) | ((uint_t)f2b(spk[5]) << 16);
        pq.w = (uint_t)f2b(spk[6]) | ((uint_t)f2b(spk[7]) << 16);
        *(uint4*)(base_out + (size_t)s * T_DATA + tbase) = pb;
        *(uint4*)(spk_out + (size_t)s * T_DATA + tbase) = pq;
    } else {
        #pragma unroll
        for (int r = 0; r < RPT; ++r) {
            int t = tbase + r;
            if (t < T_DATA) {
                base_out[(size_t)s * T_DATA + t] = f2b(acc[r]);
                spk_out[(size_t)s * T_DATA + t] = f2b(spk[r]);
            }
        }
    }
}

// ---------------- kernel 3: tree gather + MLP + outputs ----------------
__global__ __launch_bounds__(256) void k3_mlp(
        const ushort_t* __restrict__ base_out, const ushort_t* __restrict__ spk_out,
        const void* __restrict__ C_den, const void* __restrict__ Theta,
        const void* __restrict__ Vo,
        const void* __restrict__ w1, const void* __restrict__ w2,
        const void* __restrict__ w3,
        const void* __restrict__ Tau,
        void* __restrict__ dout) {
    __shared__ float cd[400], th[20], W1[120], W2[36], W3[120];
    __shared__ float vo;
    __shared__ int smode;
    int tid = threadIdx.x;
    if (tid == 0) smode = detect_mode(Tau);
    __syncthreads();
    int mode = smode;
    for (int i = tid; i < 400; i += 256) cd[i] = ldin(C_den, i, mode);
    if (tid < 20) th[tid] = ldin(Theta, tid, mode);
    if (tid < 120) W1[tid] = ldin(w1, tid, mode);
    if (tid < 36) W2[tid] = ldin(w2, tid, mode);
    if (tid >= 128 && tid < 248) W3[tid - 128] = ldin(w3, tid - 128, mode);
    if (tid == 0) vo = ldin(Vo, 0, mode);
    __syncthreads();
    int t = blockIdx.x * 256 + tid;
    if (t >= T_DATA) return;
    float sv[20], bv[20];
    #pragma unroll
    for (int c = 0; c < 20; ++c) {
        sv[c] = b2f(spk_out[(size_t)c * T_DATA + t]);
        bv[c] = b2f(base_out[(size_t)c * T_DATA + t]);
    }
    stout(dout, (size_t)t, sv[0] + vo, mode);
    #pragma unroll
    for (int p = 0; p < 20; ++p) {
        float ps = 0.f;
        #pragma unroll
        for (int c = 0; c < 20; ++c) ps += cd[p * 20 + c] * sv[c];
        float x = bv[p] + th[p] + ps;
        float h0 = x >= 0.f ? x : 0.01f * x;
        float h1[6];
        #pragma unroll
        for (int k = 0; k < 6; ++k) {
            float y = h0 * W1[p * 6 + k];
            h1[k] = y >= 0.f ? y : 0.01f * y;
        }
        float zacc = 0.f;
        #pragma unroll
        for (int j = 0; j < 6; ++j) {
            float a = 0.f;
            #pragma unroll
            for (int k = 0; k < 6; ++k) a += h1[k] * W2[k * 6 + j];
            float h2 = a >= 0.f ? a : 0.01f * a;
            zacc += h2 * W3[j * 20 + p];
        }
        float zv = 1.f / (1.f + expf(-zacc));
        stout(dout, OFF_Z + (size_t)t * SUB + p, zv, mode);
    }
}

extern "C" void kernel_launch(void* const* d_in, const int* in_sizes, int n_in,
                              void* d_out, int out_size, void* d_ws, size_t ws_size,
                              hipStream_t stream) {
    const void* S_e     = d_in[0];
    const void* S_i     = d_in[1];
    const void* Z       = d_in[2];
    const void* C_den   = d_in[3];
    const void* C_syn_e = d_in[4];
    const void* C_syn_i = d_in[5];
    const void* W_syn   = d_in[6];
    const void* W_hist  = d_in[7];
    const void* W_spk   = d_in[8];
    const void* Delta   = d_in[9];
    const void* Tau     = d_in[10];
    const void* Vo      = d_in[11];
    const void* Theta   = d_in[12];
    const void* w1      = d_in[13];
    const void* w2      = d_in[14];
    const void* w3      = d_in[15];

    char* w = (char*)d_ws;
    float*    ws_f     = (float*)(w + 64);              // 16000 f32 filters
    int*      mape     = (int*)(w + 64 + 64000);        // 2000 int
    int*      mapi     = (int*)(w + 64 + 64000 + 8000); // 400 int
    ushort_t* sigs     = (ushort_t*)(w + 73664);        // 60 * SIGSTRIDE bf16
    ushort_t* base_out = (ushort_t*)(w + 12350144);     // [20][T] bf16
    ushort_t* spk_out  = (ushort_t*)(w + 16350144);     // [20][T] bf16 (end 20350144 B)

    hipLaunchKernelGGL(k0_prep, dim3(158), dim3(256), 0, stream,
                       C_syn_e, C_syn_i, W_syn, W_hist, W_spk, Delta, Tau,
                       ws_f, mape, mapi, sigs, d_out);
    hipLaunchKernelGGL(k1_reduce, dim3(T_DATA / TSPAN), dim3(256), 0, stream,
                       S_e, S_i, Z, mape, mapi, Tau, sigs);
    hipLaunchKernelGGL(k2_conv, dim3((T_DATA + TILE - 1) / TILE, SUB), dim3(256), 0, stream,
                       sigs, ws_f, base_out, spk_out);
    hipLaunchKernelGGL(k3_mlp, dim3((T_DATA + 255) / 256), dim3(256), 0, stream,
                       base_out, spk_out, C_den, Theta, Vo, w1, w2, w3, Tau, d_out);
}

// Round 7
// 270.345 us; speedup vs baseline: 2.0878x; 1.0049x over previous
//
#include <hip/hip_runtime.h>

typedef unsigned short ushort_t;
typedef unsigned int uint_t;
typedef float __attribute__((ext_vector_type(4))) f32x4;

#define T_DATA 100000
#define E_NO 2000
#define I_NO 400
#define SUB 20
#define TNO 200
#define NBASIS 19
#define HEAD 256
#define TAILPAD 2048
#define SIGSTRIDE (HEAD + T_DATA + TAILPAD)   // 102304 bf16 per (signal, subunit)
#define TILE 2048
#define RPT 8
#define TSPAN 32                               // rows per k1 block (100000 = 3125*32)
#define ACCSTR 36                              // padded t-stride for k1 LDS acc

#define OFF_Z  ((size_t)T_DATA)                       // element offset of final_Z
#define OFF_F  ((size_t)T_DATA + (size_t)T_DATA*SUB)  // element offset of out_filters

__device__ __forceinline__ float b2f(ushort_t u) {
    union { uint_t i; float f; } v; v.i = ((uint_t)u) << 16; return v.f;
}
__device__ __forceinline__ ushort_t f2b(float f) {
    union { uint_t i; float f_; } v; v.f_ = f;
    uint_t b = v.i;
    uint_t r = (b + 0x7FFFu + ((b >> 16) & 1u)) >> 16;
    return (ushort_t)r;
}
// mode: 1 = bf16 buffers, 0 = f32 buffers
__device__ __forceinline__ float ldin(const void* p, size_t idx, int mode) {
    return mode ? b2f(((const ushort_t*)p)[idx]) : ((const float*)p)[idx];
}
__device__ __forceinline__ void stout(void* p, size_t idx, float val, int mode) {
    if (mode) ((ushort_t*)p)[idx] = f2b(val);
    else      ((float*)p)[idx] = val;
}
__device__ __forceinline__ float f4get(const float4& v, int i) {
    return i == 0 ? v.x : i == 1 ? v.y : i == 2 ? v.z : v.w;
}
__device__ __forceinline__ float pick12(const float4& L, const float4& M, const float4& H, int e) {
    return e < 4 ? f4get(L, e) : e < 8 ? f4get(M, e - 4) : f4get(H, e - 8);
}
// dtype probe: Tau_spk ~3.0 each. bf16: all 20 ushorts decode to [1.5,6);
// f32: only the 10 odd (high-half) ushorts do.
__device__ __forceinline__ int detect_mode(const void* tau) {
    const ushort_t* tu = (const ushort_t*)tau;
    int cnt = 0;
    #pragma unroll
    for (int i = 0; i < 20; ++i) {
        float v = b2f(tu[i]);
        if (v >= 1.5f && v < 6.0f) cnt++;
    }
    return (cnt >= 15) ? 1 : 0;
}

// ---------------- kernel 0: basis/filters, maps, pad zeroing ----------------
__global__ __launch_bounds__(256) void k0_prep(
        const void* Csyn_e, const void* Csyn_i,
        const void* W_syn, const void* W_hist,
        const void* W_spk, const void* Delta, const void* Tau,
        float* ws_f, int* mape, int* mapi, ushort_t* sigs, void* dout) {
    __shared__ int smode;
    int bid = blockIdx.x, tid = threadIdx.x;
    if (tid == 0) smode = detect_mode(Tau);
    __syncthreads();
    int mode = smode;
    if (bid < 80) {                       // filter rows: bid = kidx*20 + s
        int kidx = bid / 20, s = bid % 20;
        int tau = tid;
        if (tau < TNO) {
            float val;
            if (kidx < 3) {
                float raw = 5.0f * logf((float)tau + 1.0f);
                val = 0.f;
                for (int b = 0; b < NBASIS; ++b) {
                    float phi = 1.5707963267948966f * (float)b;
                    float d = raw - phi;
                    float basis = (d >= -3.14159265358979f && d <= 3.14159265358979f)
                                  ? (0.5f * cosf(d) + 0.5f) : 0.f;
                    float w = (kidx == 0) ? ldin(W_syn, (size_t)s * NBASIS * 2 + b * 2 + 0, mode)
                            : (kidx == 1) ? ldin(W_syn, (size_t)s * NBASIS * 2 + b * 2 + 1, mode)
                                          : ldin(W_hist, (size_t)s * NBASIS + b, mode);
                    val += w * basis;
                }
            } else {
                float dl = ldin(Delta, s, mode), tu = ldin(Tau, s, mode), wk = ldin(W_spk, s, mode);
                float t = fmaxf((float)tau - dl, 0.f);
                float tt = t / (tu * tu);
                val = tt * expf(-tt) * (wk * wk);
            }
            ws_f[kidx * 4000 + s * TNO + tau] = val;
            stout(dout, OFF_F + (size_t)bid * TNO + tau, val, mode);
        }
    } else if (bid < 96) {                // map_e
        int e = (bid - 80) * 256 + tid;
        if (e < E_NO) {
            int m = 0;
            for (int s = 0; s < SUB; ++s)
                if (ldin(Csyn_e, (size_t)s * E_NO + e, mode) != 0.f) { m = s; break; }
            mape[e] = m;
        }
    } else if (bid < 98) {                // map_i
        int e = (bid - 96) * 256 + tid;
        if (e < I_NO) {
            int m = 0;
            for (int s = 0; s < SUB; ++s)
                if (ldin(Csyn_i, (size_t)s * I_NO + e, mode) != 0.f) { m = s; break; }
            mapi[e] = m;
        }
    } else if (bid < 158) {               // zero head+tail pads: 60 regions
        int rg = bid - 98;                // 0..59 = sig*20 + s
        int sg = rg / 20, s = rg % 20;
        ushort_t* p = sigs + (size_t)sg * SUB * SIGSTRIDE + (size_t)s * SIGSTRIDE;
        for (int i = tid; i < HEAD; i += 256) p[i] = 0;
        for (int i = tid; i < TAILPAD; i += 256) p[HEAD + T_DATA + i] = 0;
    }
}

// ---------------- kernel 1 v6: 32-row span, software-pipelined f32 stream ----------
// f32 path: 8-row unrolled 2-stage pipeline — process buffer A (rows r0..r0+3)
// while buffer B (rows r0+4..r0+7) loads are in flight, and issue the next A
// before processing B. S_e stream (83% of traffic) never drains. One barrier,
// then coalesced packed-bf16 writes (64B aligned run per sig row).
__global__ __launch_bounds__(256, 4) void k1_reduce(
        const void* __restrict__ S_e, const void* __restrict__ S_i,
        const void* __restrict__ Z,
        const int* __restrict__ mape, const int* __restrict__ mapi,
        const void* __restrict__ Tau,
        ushort_t* __restrict__ sigs) {
    __shared__ float acc[60 * ACCSTR];
    __shared__ int smode;
    int tid = threadIdx.x;
    if (tid == 0) smode = detect_mode(Tau);
    for (int i = tid; i < 60 * ACCSTR; i += 256) acc[i] = 0.f;
    __syncthreads();
    int mode = smode;

    // hoist bucket indices to registers (loop-invariant per thread)
    int be[8], bi8[8];
    if (mode) {
        if (tid < 250) {
            #pragma unroll
            for (int j = 0; j < 8; ++j) be[j] = mape[tid * 8 + j] * ACCSTR;
        }
        if (tid < 50) {
            #pragma unroll
            for (int j = 0; j < 8; ++j) bi8[j] = (20 + mapi[tid * 8 + j]) * ACCSTR;
        }
    } else {
        if (tid < 250) {
            #pragma unroll
            for (int j = 0; j < 4; ++j) be[j] = mape[tid * 4 + j] * ACCSTR;
            #pragma unroll
            for (int j = 0; j < 4; ++j) be[4 + j] = mape[(tid + 250) * 4 + j] * ACCSTR;
        }
        if (tid < 100) {
            #pragma unroll
            for (int j = 0; j < 4; ++j) bi8[j] = (20 + mapi[tid * 4 + j]) * ACCSTR;
        }
    }

    int base = blockIdx.x * TSPAN;
    if (mode) {
        for (int r0 = 0; r0 < TSPAN; r0 += 4) {
            uint4 u[4];
            uint4 w[4];
            float zv[4];
            if (tid < 250) {
                #pragma unroll
                for (int k = 0; k < 4; ++k)
                    u[k] = *(const uint4*)((const ushort_t*)S_e +
                                           (size_t)(base + r0 + k) * E_NO + tid * 8);
            }
            if (tid < 50) {
                #pragma unroll
                for (int k = 0; k < 4; ++k)
                    w[k] = *(const uint4*)((const ushort_t*)S_i +
                                           (size_t)(base + r0 + k) * I_NO + tid * 8);
            }
            if (tid >= 192 && tid < 212) {
                int s = tid - 192;
                #pragma unroll
                for (int k = 0; k < 4; ++k)
                    zv[k] = b2f(((const ushort_t*)Z)[(size_t)(base + r0 + k) * SUB + s]);
            }
            if (tid < 250) {
                #pragma unroll
                for (int k = 0; k < 4; ++k) {
                    int rl = r0 + k;
                    uint_t wd[4] = {u[k].x, u[k].y, u[k].z, u[k].w};
                    #pragma unroll
                    for (int q = 0; q < 4; ++q) {
                        float a = b2f((ushort_t)(wd[q] & 0xFFFF));
                        float b = b2f((ushort_t)(wd[q] >> 16));
                        if (a != 0.f) atomicAdd(&acc[be[2 * q] + rl], a);
                        if (b != 0.f) atomicAdd(&acc[be[2 * q + 1] + rl], b);
                    }
                }
            }
            if (tid < 50) {
                #pragma unroll
                for (int k = 0; k < 4; ++k) {
                    int rl = r0 + k;
                    uint_t wd[4] = {w[k].x, w[k].y, w[k].z, w[k].w};
                    #pragma unroll
                    for (int q = 0; q < 4; ++q) {
                        float a = b2f((ushort_t)(wd[q] & 0xFFFF));
                        float b = b2f((ushort_t)(wd[q] >> 16));
                        if (a != 0.f) atomicAdd(&acc[bi8[2 * q] + rl], a);
                        if (b != 0.f) atomicAdd(&acc[bi8[2 * q + 1] + rl], b);
                    }
                }
            }
            if (tid >= 192 && tid < 212) {
                int s = tid - 192;
                #pragma unroll
                for (int k = 0; k < 4; ++k)
                    acc[(40 + s) * ACCSTR + r0 + k] = zv[k];
            }
        }
    } else {
        f32x4 uA[8], uB[8];
        f32x4 wv[4];
        float zv[4];
        const float* Sef = (const float*)S_e;
        const float* Sif = (const float*)S_i;
        const float* Zf  = (const float*)Z;
        bool le = (tid < 250);
        bool li = (tid < 100);
        bool lz = (tid >= 192 && tid < 212);
        // prologue: rows base..base+3 into A
        if (le) {
            #pragma unroll
            for (int k = 0; k < 4; ++k) {
                const float* pe = Sef + (size_t)(base + k) * E_NO;
                uA[2 * k]     = __builtin_nontemporal_load((const f32x4*)(pe + tid * 4));
                uA[2 * k + 1] = __builtin_nontemporal_load((const f32x4*)(pe + (tid + 250) * 4));
            }
        }
        for (int r0 = 0; r0 < TSPAN; r0 += 8) {
            // issue B: rows r0+4..r0+7
            if (le) {
                #pragma unroll
                for (int k = 0; k < 4; ++k) {
                    const float* pe = Sef + (size_t)(base + r0 + 4 + k) * E_NO;
                    uB[2 * k]     = __builtin_nontemporal_load((const f32x4*)(pe + tid * 4));
                    uB[2 * k + 1] = __builtin_nontemporal_load((const f32x4*)(pe + (tid + 250) * 4));
                }
            }
            if (li) {
                #pragma unroll
                for (int k = 0; k < 4; ++k)
                    wv[k] = __builtin_nontemporal_load(
                        (const f32x4*)(Sif + (size_t)(base + r0 + k) * I_NO + tid * 4));
            }
            if (lz) {
                int s = tid - 192;
                #pragma unroll
                for (int k = 0; k < 4; ++k)
                    zv[k] = Zf[(size_t)(base + r0 + k) * SUB + s];
            }
            // process A: rows r0..r0+3
            if (le) {
                #pragma unroll
                for (int k = 0; k < 4; ++k) {
                    int rl = r0 + k;
                    #pragma unroll
                    for (int q = 0; q < 4; ++q) {
                        float a = uA[2 * k][q];
                        float b = uA[2 * k + 1][q];
                        if (a != 0.f) atomicAdd(&acc[be[q] + rl], a);
                        if (b != 0.f) atomicAdd(&acc[be[4 + q] + rl], b);
                    }
                }
            }
            if (li) {
                #pragma unroll
                for (int k = 0; k < 4; ++k) {
                    int rl = r0 + k;
                    #pragma unroll
                    for (int q = 0; q < 4; ++q) {
                        float c = wv[k][q];
                        if (c != 0.f) atomicAdd(&acc[bi8[q] + rl], c);
                    }
                }
            }
            if (lz) {
                int s = tid - 192;
                #pragma unroll
                for (int k = 0; k < 4; ++k)
                    acc[(40 + s) * ACCSTR + r0 + k] = zv[k];
            }
            // issue next A: rows r0+8..r0+11
            if (r0 + 8 < TSPAN && le) {
                #pragma unroll
                for (int k = 0; k < 4; ++k) {
                    const float* pe = Sef + (size_t)(base + r0 + 8 + k) * E_NO;
                    uA[2 * k]     = __builtin_nontemporal_load((const f32x4*)(pe + tid * 4));
                    uA[2 * k + 1] = __builtin_nontemporal_load((const f32x4*)(pe + (tid + 250) * 4));
                }
            }
            if (li) {
                #pragma unroll
                for (int k = 0; k < 4; ++k)
                    wv[k] = __builtin_nontemporal_load(
                        (const f32x4*)(Sif + (size_t)(base + r0 + 4 + k) * I_NO + tid * 4));
            }
            if (lz) {
                int s = tid - 192;
                #pragma unroll
                for (int k = 0; k < 4; ++k)
                    zv[k] = Zf[(size_t)(base + r0 + 4 + k) * SUB + s];
            }
            // process B: rows r0+4..r0+7
            if (le) {
                #pragma unroll
                for (int k = 0; k < 4; ++k) {
                    int rl = r0 + 4 + k;
                    #pragma unroll
                    for (int q = 0; q < 4; ++q) {
                        float a = uB[2 * k][q];
                        float b = uB[2 * k + 1][q];
                        if (a != 0.f) atomicAdd(&acc[be[q] + rl], a);
                        if (b != 0.f) atomicAdd(&acc[be[4 + q] + rl], b);
                    }
                }
            }
            if (li) {
                #pragma unroll
                for (int k = 0; k < 4; ++k) {
                    int rl = r0 + 4 + k;
                    #pragma unroll
                    for (int q = 0; q < 4; ++q) {
                        float c = wv[k][q];
                        if (c != 0.f) atomicAdd(&acc[bi8[q] + rl], c);
                    }
                }
            }
            if (lz) {
                int s = tid - 192;
                #pragma unroll
                for (int k = 0; k < 4; ++k)
                    acc[(40 + s) * ACCSTR + r0 + 4 + k] = zv[k];
            }
        }
    }
    __syncthreads();

    // Phase B: 60 signal rows x 32 t, packed bf16, 4 t per uint2 store.
    // 8 consecutive threads cover one sig row's 64B aligned run.
    for (int idx = tid; idx < 60 * (TSPAN / 4); idx += 256) {
        int sig = idx >> 3;                // / 8
        int g = idx & 7;
        int t0 = g * 4;
        const float* src = &acc[sig * ACCSTR + t0];
        float4 v = *(const float4*)src;
        uint2 o;
        o.x = (uint_t)f2b(v.x) | ((uint_t)f2b(v.y) << 16);
        o.y = (uint_t)f2b(v.z) | ((uint_t)f2b(v.w) << 16);
        *(uint2*)(sigs + (size_t)sig * SIGSTRIDE + HEAD + base + t0) = o;
    }
}

// ---------------- kernel 2: 4x 200-tap depthwise FIR, f32 accum ----------------
__global__ __launch_bounds__(256) void k2_conv(
        const ushort_t* __restrict__ sigs, const float* __restrict__ ws_f,
        ushort_t* __restrict__ base_out, ushort_t* __restrict__ spk_out) {
    __shared__ float X[3 * 2248 + 800];
    float* XE = X;
    float* XI = X + 2248;
    float* ZZ = X + 4496;
    float* KK = X + 6744;
    int s = blockIdx.y;
    int t0 = blockIdx.x * TILE;
    int tid = threadIdx.x;

    for (int k = 0; k < 4; ++k)
        for (int j = tid; j < TNO; j += 256)
            KK[k * TNO + j] = ws_f[k * 4000 + s * TNO + j];

    {
        const ushort_t* g0 = sigs + (size_t)s * SIGSTRIDE + (HEAD - 200) + t0;
        const ushort_t* g1 = g0 + (size_t)SUB * SIGSTRIDE;
        const ushort_t* g2 = g0 + (size_t)2 * SUB * SIGSTRIDE;
        for (int v = tid; v < 281; v += 256) {
            uint4 u = *(const uint4*)(g0 + v * 8);
            float* d = XE + v * 8;
            d[0]=b2f((ushort_t)(u.x&0xFFFF)); d[1]=b2f((ushort_t)(u.x>>16));
            d[2]=b2f((ushort_t)(u.y&0xFFFF)); d[3]=b2f((ushort_t)(u.y>>16));
            d[4]=b2f((ushort_t)(u.z&0xFFFF)); d[5]=b2f((ushort_t)(u.z>>16));
            d[6]=b2f((ushort_t)(u.w&0xFFFF)); d[7]=b2f((ushort_t)(u.w>>16));
        }
        for (int v = tid; v < 281; v += 256) {
            uint4 u = *(const uint4*)(g1 + v * 8);
            float* d = XI + v * 8;
            d[0]=b2f((ushort_t)(u.x&0xFFFF)); d[1]=b2f((ushort_t)(u.x>>16));
            d[2]=b2f((ushort_t)(u.y&0xFFFF)); d[3]=b2f((ushort_t)(u.y>>16));
            d[4]=b2f((ushort_t)(u.z&0xFFFF)); d[5]=b2f((ushort_t)(u.z>>16));
            d[6]=b2f((ushort_t)(u.w&0xFFFF)); d[7]=b2f((ushort_t)(u.w>>16));
        }
        for (int v = tid; v < 281; v += 256) {
            uint4 u = *(const uint4*)(g2 + v * 8);
            float* d = ZZ + v * 8;
            d[0]=b2f((ushort_t)(u.x&0xFFFF)); d[1]=b2f((ushort_t)(u.x>>16));
            d[2]=b2f((ushort_t)(u.y&0xFFFF)); d[3]=b2f((ushort_t)(u.y>>16));
            d[4]=b2f((ushort_t)(u.z&0xFFFF)); d[5]=b2f((ushort_t)(u.z>>16));
            d[6]=b2f((ushort_t)(u.w&0xFFFF)); d[7]=b2f((ushort_t)(u.w>>16));
        }
    }
    __syncthreads();

    float acc[RPT] = {0,0,0,0,0,0,0,0};
    float spk[RPT] = {0,0,0,0,0,0,0,0};
    const float4* XE4 = (const float4*)XE;
    const float4* XI4 = (const float4*)XI;
    const float4* ZZ4 = (const float4*)ZZ;
    const float4* KE4 = (const float4*)(KK);
    const float4* KI4 = (const float4*)(KK + 200);
    const float4* KH4 = (const float4*)(KK + 400);
    const float4* KS4 = (const float4*)(KK + 600);
    int w4 = 2 * tid + 49;                 // float4 index of window base W = 8*tid+196
    float4 eL = XE4[w4], eM = XE4[w4 + 1], eH = XE4[w4 + 2];
    float4 iL = XI4[w4], iM = XI4[w4 + 1], iH = XI4[w4 + 2];
    float4 zL = ZZ4[w4], zM = ZZ4[w4 + 1], zH = ZZ4[w4 + 2];

    for (int c = 0; c < 50; ++c) {
        if (c > 0) {
            eH = eM; eM = eL; eL = XE4[w4 - c];
            iH = iM; iM = iL; iL = XI4[w4 - c];
            zH = zM; zM = zL; zL = ZZ4[w4 - c];
        }
        float4 ke = KE4[c], ki = KI4[c], kh = KH4[c], ks = KS4[c];
        #pragma unroll
        for (int u = 0; u < 4; ++u) {
            float keu = f4get(ke, u), kiu = f4get(ki, u);
            float khu = f4get(kh, u), ksu = f4get(ks, u);
            #pragma unroll
            for (int r = 0; r < RPT; ++r) {
                float xe = pick12(eL, eM, eH, 4 + r - u);
                float xi = pick12(iL, iM, iH, 4 + r - u);
                float zz = pick12(zL, zM, zH, 3 + r - u);
                acc[r] += keu * xe;
                acc[r] += kiu * xi;
                acc[r] += khu * zz;
                spk[r] += ksu * zz;
            }
        }
    }
    int tbase = t0 + RPT * tid;
    if (tbase + RPT <= T_DATA) {
        uint4 pb, pq;
        pb.x = (uint_t)f2b(acc[0]) | ((uint_t)f2b(acc[1]) << 16);
        pb.y = (uint_t)f2b(acc[2]) | ((uint_t)f2b(acc[3]) << 16);
        pb.z = (uint_t)f2b(acc[4]) | ((uint_t)f2b(acc[5]) << 16);
        pb.w = (uint_t)f2b(acc[6]) | ((uint_t)f2b(acc[7]) << 16);
        pq.x = (uint_t)f2b(spk[0]) | ((uint_t)f2b(spk[1]) << 16);
        pq.y = (uint_t)f2b(spk[2]) | ((uint_t)f2b(spk[3]) << 16);
        pq.z = (uint_t)f2b(spk[4]) | ((uint_t)f2b(spk[5]) << 16);
        pq.w = (uint_t)f2b(spk[6]) | ((uint_t)f2b(spk[7]) << 16);
        *(uint4*)(base_out + (size_t)s * T_DATA + tbase) = pb;
        *(uint4*)(spk_out + (size_t)s * T_DATA + tbase) = pq;
    } else {
        #pragma unroll
        for (int r = 0; r < RPT; ++r) {
            int t = tbase + r;
            if (t < T_DATA) {
                base_out[(size_t)s * T_DATA + t] = f2b(acc[r]);
                spk_out[(size_t)s * T_DATA + t] = f2b(spk[r]);
            }
        }
    }
}

// ---------------- kernel 3: tree gather + MLP + outputs ----------------
__global__ __launch_bounds__(256) void k3_mlp(
        const ushort_t* __restrict__ base_out, const ushort_t* __restrict__ spk_out,
        const void* __restrict__ C_den, const void* __restrict__ Theta,
        const void* __restrict__ Vo,
        const void* __restrict__ w1, const void* __restrict__ w2,
        const void* __restrict__ w3,
        const void* __restrict__ Tau,
        void* __restrict__ dout) {
    __shared__ float cd[400], th[20], W1[120], W2[36], W3[120];
    __shared__ float vo;
    __shared__ int smode;
    int tid = threadIdx.x;
    if (tid == 0) smode = detect_mode(Tau);
    __syncthreads();
    int mode = smode;
    for (int i = tid; i < 400; i += 256) cd[i] = ldin(C_den, i, mode);
    if (tid < 20) th[tid] = ldin(Theta, tid, mode);
    if (tid < 120) W1[tid] = ldin(w1, tid, mode);
    if (tid < 36) W2[tid] = ldin(w2, tid, mode);
    if (tid >= 128 && tid < 248) W3[tid - 128] = ldin(w3, tid - 128, mode);
    if (tid == 0) vo = ldin(Vo, 0, mode);
    __syncthreads();
    int t = blockIdx.x * 256 + tid;
    if (t >= T_DATA) return;
    float sv[20], bv[20];
    #pragma unroll
    for (int c = 0; c < 20; ++c) {
        sv[c] = b2f(spk_out[(size_t)c * T_DATA + t]);
        bv[c] = b2f(base_out[(size_t)c * T_DATA + t]);
    }
    stout(dout, (size_t)t, sv[0] + vo, mode);
    #pragma unroll
    for (int p = 0; p < 20; ++p) {
        float ps = 0.f;
        #pragma unroll
        for (int c = 0; c < 20; ++c) ps += cd[p * 20 + c] * sv[c];
        float x = bv[p] + th[p] + ps;
        float h0 = x >= 0.f ? x : 0.01f * x;
        float h1[6];
        #pragma unroll
        for (int k = 0; k < 6; ++k) {
            float y = h0 * W1[p * 6 + k];
            h1[k] = y >= 0.f ? y : 0.01f * y;
        }
        float zacc = 0.f;
        #pragma unroll
        for (int j = 0; j < 6; ++j) {
            float a = 0.f;
            #pragma unroll
            for (int k = 0; k < 6; ++k) a += h1[k] * W2[k * 6 + j];
            float h2 = a >= 0.f ? a : 0.01f * a;
            zacc += h2 * W3[j * 20 + p];
        }
        float zv = 1.f / (1.f + expf(-zacc));
        stout(dout, OFF_Z + (size_t)t * SUB + p, zv, mode);
    }
}

extern "C" void kernel_launch(void* const* d_in, const int* in_sizes, int n_in,
                              void* d_out, int out_size, void* d_ws, size_t ws_size,
                              hipStream_t stream) {
    const void* S_e     = d_in[0];
    const void* S_i     = d_in[1];
    const void* Z       = d_in[2];
    const void* C_den   = d_in[3];
    const void* C_syn_e = d_in[4];
    const void* C_syn_i = d_in[5];
    const void* W_syn   = d_in[6];
    const void* W_hist  = d_in[7];
    const void* W_spk   = d_in[8];
    const void* Delta   = d_in[9];
    const void* Tau     = d_in[10];
    const void* Vo      = d_in[11];
    const void* Theta   = d_in[12];
    const void* w1      = d_in[13];
    const void* w2      = d_in[14];
    const void* w3      = d_in[15];

    char* w = (char*)d_ws;
    float*    ws_f     = (float*)(w + 64);              // 16000 f32 filters
    int*      mape     = (int*)(w + 64 + 64000);        // 2000 int
    int*      mapi     = (int*)(w + 64 + 64000 + 8000); // 400 int
    ushort_t* sigs     = (ushort_t*)(w + 73664);        // 60 * SIGSTRIDE bf16
    ushort_t* base_out = (ushort_t*)(w + 12350144);     // [20][T] bf16
    ushort_t* spk_out  = (ushort_t*)(w + 16350144);     // [20][T] bf16 (end 20350144 B)

    hipLaunchKernelGGL(k0_prep, dim3(158), dim3(256), 0, stream,
                       C_syn_e, C_syn_i, W_syn, W_hist, W_spk, Delta, Tau,
                       ws_f, mape, mapi, sigs, d_out);
    hipLaunchKernelGGL(k1_reduce, dim3(T_DATA / TSPAN), dim3(256), 0, stream,
                       S_e, S_i, Z, mape, mapi, Tau, sigs);
    hipLaunchKernelGGL(k2_conv, dim3((T_DATA + TILE - 1) / TILE, SUB), dim3(256), 0, stream,
                       sigs, ws_f, base_out, spk_out);
    hipLaunchKernelGGL(k3_mlp, dim3((T_DATA + 255) / 256), dim3(256), 0, stream,
                       base_out, spk_out, C_den, Theta, Vo, w1, w2, w3, Tau, d_out);
}